// Round 15
// baseline (152.006 us; speedup 1.0000x reference)
//
#include <hip/hip_runtime.h>

// B=64, S=63, F=64, T=12, NF=63, OUT=1, C=32, K=3, DILS=(1,2,4,8,16)
//
// R15: SINGLE fused kernel, 3 block roles:
//   blk <  4096 : compute (R13 MFMA pyramid, coalesced per-block weight staging)
//   blk <  4328 : tables (RECH 18 chunks / PRM / XFT)
//   blk >= 4328 : seq chains (R13 tcn_seq), spin-waiting on device counters:
//                 ctrT(=232) -> stage weights/params/xv; ctrC(=4096) -> state+chain.
// Producers: syncthreads -> __threadfence (agent release) -> atomicAdd.
// Consumers: relaxed polls + one acquire fence (L2 invalidate) after exit.
// Counters zeroed via 8-byte hipMemsetAsync each launch (graph-capturable).

typedef _Float16 f16;
typedef _Float16 h2 __attribute__((ext_vector_type(2)));
typedef _Float16 f16x4 __attribute__((ext_vector_type(4)));
typedef _Float16 f16x8 __attribute__((ext_vector_type(8)));
typedef float f32x16 __attribute__((ext_vector_type(16)));

// ---------------- workspace layout (float offsets) ----------------
#define OFF_H4    0                        // h4T [64][3][64][4] = 49152
#define OFF_ST    49152                    // feature-63 state, per-b stride 1760
#define ST_L0     0
#define ST_L1     128
#define ST_L2     384
#define ST_L3     896
#define ST_STRIDE 1760                     // ends 161792
#define OFF_H40   161792                   // [64]
#define OFF_RECH  161856                   // f16 rech[18][64][8] = 9216 f16 = 4608 fl
#define OFF_PRM   166464                   // prm[4][64][4] f32 = 1024
#define OFF_XFT   167488                   // xfcT[64][3][64][4] = 49152 -> 216640
#define OFF_CTR   216640                   // int ctr[2]: [0]=compute, [1]=tables

#define RECH_N 9216
#define TAIL_N 59392                       // 9216 + 1024 + 49152 = 232 blocks
#define NCOMP  4096
#define NTAIL  232
#define NSEQ   64

#define RPAD 36
#define NROW 100

#if __has_builtin(__builtin_amdgcn_fence)
#define ACQ_FENCE() __builtin_amdgcn_fence(__ATOMIC_ACQUIRE, "agent")
#else
#define ACQ_FENCE() __threadfence()
#endif

// ---- LDS union (max(pre 21504, seq 25456) = 25456 -> 25472) ----
#define SMEM_BYTES 25472
// pre:  sIn@0(320) sBias@320(384) actA@704(7200) actB@7904(7200) wrow@15104(6400)
// seq:  wseqh@0(18432) L0h@18432(960) L1p0@19392(1216) L1p1@20608(1216)
//       L2p0@21824(1728) L2p1@23552(1728) qs@25280(128) preArr@25408(48)

// ---------------- per-block weight-row staging (coalesced) ----------------
__device__ __forceinline__ void stage_wrow(
    const float* __restrict__ wmid, int m, int f, int tid, f16* wrow)
{
  const float* src = wmid + m * 196608 + f * 3072 + tid * 12;
  f16* dst = wrow + (tid >> 3) * 100 + (tid & 7) * 12;
#pragma unroll
  for (int u = 0; u < 3; ++u) {
    const float4 v = *reinterpret_cast<const float4*>(src + u * 4);
    dst[u * 4 + 0] = (f16)v.x; dst[u * 4 + 1] = (f16)v.y;
    dst[u * 4 + 2] = (f16)v.z; dst[u * 4 + 3] = (f16)v.w;
  }
}

// ---------------- MFMA tile; fragments built from LDS wrow ----------------
__device__ __forceinline__ void mfma_tile2(
    const f16* IN, f16* OUT, int d, int base,
    const f16* __restrict__ wrow, int lane, const float* sBias)
{
  const int lg = lane >> 5;
  const int co = lane & 31;
  const int col = base + co;

  f16x8 afr[6];
#pragma unroll
  for (int h = 0; h < 2; ++h) {
    const f16* wp = wrow + co * 100 + (h * 16 + lg * 8) * 3;
    f16x4 w4[6];
#pragma unroll
    for (int u = 0; u < 6; ++u) w4[u] = *(const f16x4*)(wp + u * 4);
#pragma unroll
    for (int t = 0; t < 3; ++t)
#pragma unroll
      for (int j = 0; j < 8; ++j) {
        const int o = 3 * j + t;
        afr[t * 2 + h][j] = w4[o >> 2][o & 3];
      }
  }

  f32x16 acc;
#pragma unroll
  for (int r = 0; r < 16; ++r)
    acc[r] = sBias[(r & 3) + 8 * (r >> 2) + 4 * lg];

#pragma unroll
  for (int t = 0; t < 3; ++t) {
#pragma unroll
    for (int h = 0; h < 2; ++h) {
      const f16* bp = IN + (col + t * d) * RPAD + h * 16 + lg * 8;
      f16x4 lo = *(const f16x4*)bp;
      f16x4 hi = *(const f16x4*)(bp + 4);
      f16x8 b = __builtin_shufflevector(lo, hi, 0, 1, 2, 3, 4, 5, 6, 7);
      acc = __builtin_amdgcn_mfma_f32_32x32x16_f16(afr[t * 2 + h], b, acc, 0, 0, 0);
    }
  }

#pragma unroll
  for (int q = 0; q < 4; ++q) {
    const int co0 = q * 8 + 4 * lg;
    f16x4 w;
#pragma unroll
    for (int e = 0; e < 4; ++e)
      w[e] = (f16)fmaxf(acc[q * 4 + e], 0.f);
    *(f16x4*)(OUT + col * RPAD + co0) = w;
  }
}

// ---------------- seq helpers ----------------
__device__ __forceinline__ float fd2(h2 a, h2 b, float c) {
#if __has_builtin(__builtin_amdgcn_fdot2)
  return __builtin_amdgcn_fdot2(a, b, c, false);
#else
  return fmaf((float)a[0], (float)b[0], fmaf((float)a[1], (float)b[1], c));
#endif
}

__device__ __forceinline__ float dotv(f16x8 w, f16x8 a, float acc) {
  h2 w0 = {w[0], w[1]}, a0 = {a[0], a[1]};
  h2 w1 = {w[2], w[3]}, a1 = {a[2], a[3]};
  h2 w2 = {w[4], w[5]}, a2 = {a[4], a[5]};
  h2 w3 = {w[6], w[7]}, a3 = {a[6], a[7]};
  acc = fd2(w0, a0, acc);
  acc = fd2(w1, a1, acc);
  acc = fd2(w2, a2, acc);
  acc = fd2(w3, a3, acc);
  return acc;
}

__device__ __forceinline__ f16x8 combineh(f16x8 lo, f16x8 hi) {
  f16x8 s = lo + hi;
#pragma unroll
  for (int i = 0; i < 8; ++i) s[i] = (s[i] > (f16)0.f) ? s[i] : (f16)0.f;
  return s;
}

__device__ __forceinline__ void load16f(const float* p, float* r) {
  const float4* q = reinterpret_cast<const float4*>(p);
  const float4 v0 = q[0], v1 = q[1], v2 = q[2], v3 = q[3];
  r[0]=v0.x;  r[1]=v0.y;  r[2]=v0.z;  r[3]=v0.w;
  r[4]=v1.x;  r[5]=v1.y;  r[6]=v1.z;  r[7]=v1.w;
  r[8]=v2.x;  r[9]=v2.y;  r[10]=v2.z; r[11]=v2.w;
  r[12]=v3.x; r[13]=v3.y; r[14]=v3.z; r[15]=v3.w;
}

// ---------------- the fused kernel ----------------
__global__ __launch_bounds__(256) void tcn_all(
    const float* __restrict__ x, const float* __restrict__ xfc,
    const float* __restrict__ w0, const float* __restrict__ b0,
    const float* __restrict__ wmid, const float* __restrict__ bmid,
    const float* __restrict__ wlast, const float* __restrict__ blast,
    const float* __restrict__ linW, const float* __restrict__ linb,
    float* __restrict__ ws, float* __restrict__ out)
{
  __shared__ __align__(16) char smem[SMEM_BYTES];
  const int blk = blockIdx.x;
  const int tid = threadIdx.x;
  int* ctr = (int*)(ws + OFF_CTR);

  if (blk >= NCOMP + NTAIL) {
    // ================= SEQ role =================
    if (tid >= 64) return;               // single wave does everything
    const int b = blk - (NCOMP + NTAIL);
    const int c = tid & 31;
    const int h = tid >> 5;
    const int cib = h * 16;

    f16* wseqh = (f16*)smem;
    f16* L0h   = (f16*)(smem + 18432);
    f16* L1p0  = (f16*)(smem + 19392);
    f16* L1p1  = (f16*)(smem + 20608);
    f16* L2p0  = (f16*)(smem + 21824);
    f16* L2p1  = (f16*)(smem + 23552);
    float* qs     = (float*)(smem + 25280);
    float* preArr = (float*)(smem + 25408);

    // inputs (no dependency)
    const float xv61 = x[(b * 63 + 61) * 64 + 63];
    const float xv62 = x[(b * 63 + 62) * 64 + 63];
    float lw = 0.f, lwx = 0.f;
    if (tid < 63) { lw = linW[tid]; lwx = linW[64 + tid]; }

    // ---- wait for table blocks, then stage weights/params/xv ----
    while (__hip_atomic_load(&ctr[1], __ATOMIC_RELAXED, __HIP_MEMORY_SCOPE_AGENT) < NTAIL)
      __builtin_amdgcn_s_sleep(4);
    ACQ_FENCE();

    {
      const f16* rech = (const f16*)(ws + OFF_RECH);
#pragma unroll
      for (int q = 0; q < 18; ++q)
        *(f16x8*)(wseqh + (q * 64 + tid) * 8) = *(const f16x8*)(rech + (q * 64 + tid) * 8);
    }
    float prm[16];
    {
      const float* tab = ws + OFF_PRM;
#pragma unroll
      for (int q = 0; q < 4; ++q) {
        const float4 v = *reinterpret_cast<const float4*>(tab + (q * 64 + tid) * 4);
        prm[q * 4 + 0] = v.x; prm[q * 4 + 1] = v.y;
        prm[q * 4 + 2] = v.z; prm[q * 4 + 3] = v.w;
      }
    }
    float xv[12];
#pragma unroll
    for (int q = 0; q < 3; ++q) {
      const float4 vv = *reinterpret_cast<const float4*>(ws + OFF_XFT + b * 768 + q * 256 + tid * 4);
      xv[q*4+0] = vv.x; xv[q*4+1] = vv.y; xv[q*4+2] = vv.z; xv[q*4+3] = vv.w;
    }
    const float w00 = prm[0],  w01 = prm[1],  w02 = prm[2],  b00 = prm[3];
    const float bm0 = prm[4],  bm1 = prm[5],  bm2 = prm[6];
    const float wl0c = prm[7], wl1c = prm[8], wl2c = prm[9];
    const float bl = prm[10],  lw63 = prm[11], lb0 = prm[12];

    // ---- wait for compute blocks, then stage state + accv ----
    while (__hip_atomic_load(&ctr[0], __ATOMIC_RELAXED, __HIP_MEMORY_SCOPE_AGENT) < NCOMP)
      __builtin_amdgcn_s_sleep(4);
    ACQ_FENCE();

    const float* stp = ws + OFF_ST + b * ST_STRIDE;
    for (int t = tid; t < 128; t += 64) L0h[t] = (f16)stp[ST_L0 + t];
    for (int t = tid; t < 256; t += 64) { L1p0[t] = (f16)stp[ST_L1 + t]; L1p1[t] = (f16)0.f; }
    for (int t = tid; t < 512; t += 64) { L2p0[t] = (f16)stp[ST_L2 + t]; L2p1[t] = (f16)0.f; }
    const float h40v = ws[OFF_H40 + b];

    float accv[12];
    {
      float h4v[12];
#pragma unroll
      for (int q = 0; q < 3; ++q) {
        const float4 hv = *reinterpret_cast<const float4*>(ws + OFF_H4 + b * 768 + q * 256 + tid * 4);
        h4v[q*4+0] = hv.x; h4v[q*4+1] = hv.y; h4v[q*4+2] = hv.z; h4v[q*4+3] = hv.w;
      }
#pragma unroll
      for (int i = 0; i < 12; ++i) accv[i] = fmaf(lw, h4v[i], lwx * xv[i]);
      if (tid < 32) {
#pragma unroll
        for (int i = 1; i < 12; ++i) {
          const float qc = fmaf(wl0c, stp[ST_L3 + (i - 1) * 32 + tid],
                                wl1c * stp[ST_L3 + (i + 15) * 32 + tid]);
          accv[i] = fmaf(lw63, qc, accv[i]);
        }
      }
#pragma unroll
      for (int r = 1; r < 64; r <<= 1) {
#pragma unroll
        for (int i = 0; i < 12; ++i) accv[i] += __shfl_xor(accv[i], r);
      }
    }
    if (tid == 0) {
#pragma unroll
      for (int i = 1; i < 12; ++i) preArr[i] = accv[i] + lb0 + lw63 * bl;
    }

    // opaque pointer: keep per-iteration wseqh reads (no LICM re-hoist)
    const f16* wbase = wseqh;
    asm volatile("" : "+v"(wbase));

    // ---- step 0 ----
    const float out0 = fmaf(lw63, h40v, accv[0] + lb0);
    if (tid == 0) out[b * 12 + 0] = out0;
    float o1 = out0, o2 = xv62, o3 = xv61;

    // ---- steps 1..11 (rolled; f16 data, f32 accum) ----
#pragma unroll 1
    for (int s = 1; s < 12; ++s) {
      const float preS = preArr[s];

      const float nL0 = fmaxf(fmaf(w00, o3, fmaf(w01, o2, fmaf(w02, o1, b00))), 0.f);
      L0h[(3 + s) * 32 + c] = (f16)nL0;

      // ---- L1 @ 56+s ----
      float v1;
      {
        const f16* wp = wbase + (0 * 6 * 64 + tid) * 8;
        f16x8 W0 = *(const f16x8*)(wp);
        f16x8 W1 = *(const f16x8*)(wp + 64 * 8);
        f16x8 W2 = *(const f16x8*)(wp + 2 * 64 * 8);
        f16x8 W3 = *(const f16x8*)(wp + 3 * 64 * 8);
        f16x8 W4 = *(const f16x8*)(wp + 4 * 64 * 8);
        f16x8 W5 = *(const f16x8*)(wp + 5 * 64 * 8);
        const f16* r0p = L0h + (s - 1) * 32 + cib;
        const f16* r1p = L0h + (s + 1) * 32 + cib;
        const f16* np  = L0h + (3 + s) * 32 + cib;
        f16x8 R0a = *(const f16x8*)r0p, R0b = *(const f16x8*)(r0p + 8);
        f16x8 R1a = *(const f16x8*)r1p, R1b = *(const f16x8*)(r1p + 8);
        f16x8 Na  = *(const f16x8*)np,  Nb  = *(const f16x8*)(np + 8);
        float a0 = dotv(W0, R0a, 0.f), a1 = dotv(W1, R0b, 0.f);
        a0 = dotv(W2, R1a, a0);        a1 = dotv(W3, R1b, a1);
        a0 = dotv(W4, Na, a0);         a1 = dotv(W5, Nb, a1);
        v1 = a0 + a1 + (h == 0 ? bm0 : 0.f);
      }
      (h ? L1p1 : L1p0)[(7 + s) * 32 + c] = (f16)v1;

      // ---- L2 @ 48+s ----
      float v2;
      {
        const f16* wp = wbase + (1 * 6 * 64 + tid) * 8;
        f16x8 W0 = *(const f16x8*)(wp);
        f16x8 W1 = *(const f16x8*)(wp + 64 * 8);
        f16x8 W2 = *(const f16x8*)(wp + 2 * 64 * 8);
        f16x8 W3 = *(const f16x8*)(wp + 3 * 64 * 8);
        f16x8 W4 = *(const f16x8*)(wp + 4 * 64 * 8);
        f16x8 W5 = *(const f16x8*)(wp + 5 * 64 * 8);
        const int i0 = (s - 1) * 32 + cib, i1 = (s + 3) * 32 + cib, in = (7 + s) * 32 + cib;
        f16x8 R0a = combineh(*(const f16x8*)(L1p0 + i0),     *(const f16x8*)(L1p1 + i0));
        f16x8 R0b = combineh(*(const f16x8*)(L1p0 + i0 + 8), *(const f16x8*)(L1p1 + i0 + 8));
        f16x8 R1a = combineh(*(const f16x8*)(L1p0 + i1),     *(const f16x8*)(L1p1 + i1));
        f16x8 R1b = combineh(*(const f16x8*)(L1p0 + i1 + 8), *(const f16x8*)(L1p1 + i1 + 8));
        f16x8 Na  = combineh(*(const f16x8*)(L1p0 + in),     *(const f16x8*)(L1p1 + in));
        f16x8 Nb  = combineh(*(const f16x8*)(L1p0 + in + 8), *(const f16x8*)(L1p1 + in + 8));
        float a0 = dotv(W0, R0a, 0.f), a1 = dotv(W1, R0b, 0.f);
        a0 = dotv(W2, R1a, a0);        a1 = dotv(W3, R1b, a1);
        a0 = dotv(W4, Na, a0);         a1 = dotv(W5, Nb, a1);
        v2 = a0 + a1 + (h == 0 ? bm1 : 0.f);
      }
      (h ? L2p1 : L2p0)[(15 + s) * 32 + c] = (f16)v2;

      // ---- L3 @ 32+s ----
      float v3;
      {
        const f16* wp = wbase + (2 * 6 * 64 + tid) * 8;
        f16x8 W0 = *(const f16x8*)(wp);
        f16x8 W1 = *(const f16x8*)(wp + 64 * 8);
        f16x8 W2 = *(const f16x8*)(wp + 2 * 64 * 8);
        f16x8 W3 = *(const f16x8*)(wp + 3 * 64 * 8);
        f16x8 W4 = *(const f16x8*)(wp + 4 * 64 * 8);
        f16x8 W5 = *(const f16x8*)(wp + 5 * 64 * 8);
        const int i0 = (s - 1) * 32 + cib, i1 = (s + 7) * 32 + cib, in = (15 + s) * 32 + cib;
        f16x8 R0a = combineh(*(const f16x8*)(L2p0 + i0),     *(const f16x8*)(L2p1 + i0));
        f16x8 R0b = combineh(*(const f16x8*)(L2p0 + i0 + 8), *(const f16x8*)(L2p1 + i0 + 8));
        f16x8 R1a = combineh(*(const f16x8*)(L2p0 + i1),     *(const f16x8*)(L2p1 + i1));
        f16x8 R1b = combineh(*(const f16x8*)(L2p0 + i1 + 8), *(const f16x8*)(L2p1 + i1 + 8));
        f16x8 Na  = combineh(*(const f16x8*)(L2p0 + in),     *(const f16x8*)(L2p1 + in));
        f16x8 Nb  = combineh(*(const f16x8*)(L2p0 + in + 8), *(const f16x8*)(L2p1 + in + 8));
        float a0 = dotv(W0, R0a, 0.f), a1 = dotv(W1, R0b, 0.f);
        a0 = dotv(W2, R1a, a0);        a1 = dotv(W3, R1b, a1);
        a0 = dotv(W4, Na, a0);         a1 = dotv(W5, Nb, a1);
        v3 = a0 + a1 + (h == 0 ? bm2 : 0.f);
      }
      v3 += __shfl_xor(v3, 32);
      const float nL3 = fmaxf(v3, 0.f);

      // ---- L4 @ s ----
      if (h == 0) qs[c] = wl2c * nL3;
      float qa[16], qb[16];
      load16f(qs, qa); load16f(qs + 16, qb);
      float s0 = 0.f, s1 = 0.f, s2 = 0.f, s3 = 0.f;
#pragma unroll
      for (int i = 0; i < 16; i += 4) {
        s0 += qa[i + 0] + qb[i + 0];
        s1 += qa[i + 1] + qb[i + 1];
        s2 += qa[i + 2] + qb[i + 2];
        s3 += qa[i + 3] + qb[i + 3];
      }
      const float S = (s0 + s1) + (s2 + s3);
      const float outs = fmaf(lw63, S, preS);
      if (tid == 0) out[b * 12 + s] = outs;
      o3 = o2; o2 = o1; o1 = outs;
    }
    return;
  }

  if (blk >= NCOMP) {
    // ================= TABLE role =================
    const int idx = (blk - NCOMP) * 256 + tid;   // 0..59391
    if (idx < RECH_N) {
      const int e = idx & 7, lane = (idx >> 3) & 63, q = idx >> 9;
      const int i = q * 8 + e;
      const int m = i / 48, r2 = i % 48;
      const int k = r2 >> 4, ci = r2 & 15;
      const int c = lane & 31, cib = (lane >> 5) * 16;
      ((f16*)(ws + OFF_RECH))[idx] =
          (f16)wmid[m * 196608 + (2016 + c) * 96 + (cib + ci) * 3 + k];
    } else if (idx < RECH_N + 1024) {
      const int r = idx - RECH_N;
      const int e = r & 3, lane = (r >> 2) & 63, q = r >> 8;
      const int i = q * 4 + e;
      const int c = lane & 31;
      float v = 0.f;
      if (i < 3)        v = w0[(2016 + c) * 3 + i];
      else if (i == 3)  v = b0[2016 + c];
      else if (i < 7)   v = bmid[(i - 4) * 2048 + 2016 + c];
      else if (i < 10)  v = wlast[63 * 96 + c * 3 + (i - 7)];
      else if (i == 10) v = blast[63];
      else if (i == 11) v = linW[63];
      else if (i == 12) v = linb[0];
      ws[OFF_PRM + r] = v;
    } else {
      const int r = idx - (RECH_N + 1024);
      const int b = r / 768, rem = r % 768;
      const int q = rem >> 8, lane = (rem >> 2) & 63, e = rem & 3;
      const int i = q * 4 + e;
      ws[OFF_XFT + r] = (lane < 63 && i < 12) ? xfc[(b * 12 + i) * 63 + lane] : 0.f;
    }
    __syncthreads();
    if (tid == 0) { __threadfence(); atomicAdd(&ctr[1], 1); }
    return;
  }

  // ================= COMPUTE role =================
  const int b = blk >> 6;
  const int f = blk & 63;
  const bool lastf = (f == 63);
  const int lane = tid & 63;
  const int g = __builtin_amdgcn_readfirstlane(tid >> 6);

  float* sIn   = (float*)smem;
  float* sBias = (float*)(smem + 320);          // [3][32]
  f16*   actA  = (f16*)(smem + 704);
  f16*   actB  = (f16*)(smem + 7904);
  f16*   wrow  = (f16*)(smem + 15104);

  for (int t = tid; t < 80; t += 256) {
    float v = 0.f;
    if (t < 63)                 v = x[(b * 63 + t) * 64 + f];
    else if (t < 74 && !lastf)  v = xfc[(b * 12 + (t - 63)) * 63 + f];
    sIn[t] = v;
  }
  if (tid < 96) sBias[(tid >> 5) * 32 + (tid & 31)] = bmid[(tid >> 5) * 2048 + f * 32 + (tid & 31)];
  for (int i = tid; i < (NROW - 72) * RPAD; i += 256) actA[72 * RPAD + i] = (f16)0.f;
  for (int i = tid; i < (NROW - 68) * RPAD; i += 256) actB[68 * RPAD + i] = (f16)0.f;
  stage_wrow(wmid, 0, f, tid, wrow);
  __syncthreads();

  // ---- L0 (d=1, 1->32ch), pos 0..71 -> actA ----
  {
    const float* wb  = w0 + (f * 32 + g * 8) * 3;
    const float* bbp = b0 + f * 32 + g * 8;
#pragma unroll
    for (int it = 0; it < 2; ++it) {
      const int p = lane + it * 64;
      if (p < 72) {
        const float i0 = sIn[p], i1 = sIn[p + 1], i2 = sIn[p + 2];
        f16x4 wv[2];
#pragma unroll
        for (int j = 0; j < 8; ++j) {
          float v = fmaf(wb[j * 3 + 0], i0,
                    fmaf(wb[j * 3 + 1], i1,
                    fmaf(wb[j * 3 + 2], i2, bbp[j])));
          wv[j >> 2][j & 3] = (f16)fmaxf(v, 0.f);
        }
        *(f16x4*)(actA + p * RPAD + g * 8)     = wv[0];
        *(f16x4*)(actA + p * RPAD + g * 8 + 4) = wv[1];
      }
    }
  }
  __syncthreads();

  float* st = ws + OFF_ST + b * ST_STRIDE;

  // ---- mfma L1 (d=2) ----
  if (lastf) {
    for (int t = tid; t < 128; t += 256)
      st[ST_L0 + t] = (float)actA[(57 + (t >> 5)) * RPAD + (t & 31)];
  }
  if (g < 3) mfma_tile2(actA, actB, 2, g * 32, wrow, lane, sBias + 0);
  __syncthreads();

  stage_wrow(wmid, 1, f, tid, wrow);
  if (lastf) {
    for (int t = tid; t < 256; t += 256)
      st[ST_L1 + t] = (float)actB[(49 + (t >> 5)) * RPAD + (t & 31)];
  }
  __syncthreads();

  // ---- mfma L2 (d=4) ----
  if (g < 2) mfma_tile2(actB, actA, 4, g * 32, wrow, lane, sBias + 32);
  __syncthreads();

  stage_wrow(wmid, 2, f, tid, wrow);
  if (lastf) {
    for (int t = tid; t < 512; t += 256)
      st[ST_L2 + t] = (float)actA[(33 + (t >> 5)) * RPAD + (t & 31)];
  }
  __syncthreads();

  // ---- mfma L3 (d=8) ----
  if (g < 2) mfma_tile2(actA, actB, 8, g * 32, wrow, lane, sBias + 64);
  __syncthreads();

  // ---- L3 slice; L4 (d=16, 32->1, no relu) ----
  if (lastf) {
    for (int t = tid; t < 864; t += 256)
      st[ST_L3 + t] = (float)actB[(1 + (t >> 5)) * RPAD + (t & 31)];
  }
  if (tid < 12) {
    const int p = tid;
    float acc = blast[f];
    const float* wl = wlast + f * 96;
#pragma unroll
    for (int k = 0; k < 3; ++k) {
      const int row = p + 16 * k;
#pragma unroll
      for (int ci0 = 0; ci0 < 32; ci0 += 4) {
        f16x4 av = *(const f16x4*)(actB + row * RPAD + ci0);
#pragma unroll
        for (int e = 0; e < 4; ++e)
          acc = fmaf(wl[(ci0 + e) * 3 + k], (float)av[e], acc);
      }
    }
    if (!lastf) {
      ws[OFF_H4 + b * 768 + (p >> 2) * 256 + f * 4 + (p & 3)] = acc;
    } else {
      ws[OFF_H4 + b * 768 + (p >> 2) * 256 + 63 * 4 + (p & 3)] = 0.f;
      if (p == 0) ws[OFF_H40 + b] = acc;
    }
  }
  __syncthreads();
  if (tid == 0) { __threadfence(); atomicAdd(&ctr[0], 1); }
}

// ---------------- launcher ----------------

extern "C" void kernel_launch(void* const* d_in, const int* in_sizes, int n_in,
                              void* d_out, int out_size, void* d_ws, size_t ws_size,
                              hipStream_t stream) {
  const float* x     = (const float*)d_in[0];
  const float* xfc   = (const float*)d_in[1];
  const float* w0    = (const float*)d_in[2];
  const float* b0    = (const float*)d_in[3];
  const float* wmid  = (const float*)d_in[4];
  const float* bmid  = (const float*)d_in[5];
  const float* wlast = (const float*)d_in[6];
  const float* blast = (const float*)d_in[7];
  const float* linW  = (const float*)d_in[8];
  const float* linb  = (const float*)d_in[9];
  float* out = (float*)d_out;
  float* ws  = (float*)d_ws;

  // zero the two sync counters (graph-capturable)
  hipMemsetAsync((char*)d_ws + OFF_CTR * sizeof(float), 0, 8, stream);
  tcn_all<<<NCOMP + NTAIL + NSEQ, 256, 0, stream>>>(
      x, xfc, w0, b0, wmid, bmid, wlast, blast, linW, linb, ws, out);
}

// Round 16
// 38.118 us; speedup vs baseline: 3.9878x; 3.9878x over previous
//
#include <hip/hip_runtime.h>

// B=64, S=63, F=64, T=12, NF=63, OUT=1, C=32, K=3, DILS=(1,2,4,8,16)
//
// R16 = R13 (best: 41.85us) + 4-wave tcn_seq setup:
//  tcn_pre: 4096 compute blocks (MFMA pyramid, coalesced per-block weight
//           staging) + 232 tail blocks building RECH/PRM/XFT. Unchanged.
//  tcn_seq: 256 threads; waves 1-3 parallelize setup staging then exit;
//           wave 0 computes accv and runs the chain (R13 form, f16+fdot2).

typedef _Float16 f16;
typedef _Float16 h2 __attribute__((ext_vector_type(2)));
typedef _Float16 f16x4 __attribute__((ext_vector_type(4)));
typedef _Float16 f16x8 __attribute__((ext_vector_type(8)));
typedef float f32x16 __attribute__((ext_vector_type(16)));

// ---------------- workspace layout (float offsets) ----------------
#define OFF_H4    0                        // h4T [64][3][64][4] = 49152
#define OFF_ST    49152                    // feature-63 state, per-b stride 1760
#define ST_L0     0                        // L0 pos 57..60   (4*32)  [pos][ch]
#define ST_L1     128                      // L1 pos 49..56   (8*32)
#define ST_L2     384                      // L2 pos 33..48   (16*32)
#define ST_L3     896                      // L3 pos 1..27    (27*32)
#define ST_STRIDE 1760                     // ends 161792
#define OFF_H40   161792                   // [64]
#define OFF_RECH  161856                   // f16 rech[18][64][8] = 9216 f16 = 4608 fl
#define OFF_PRM   166464                   // prm[4][64][4] f32 = 1024
#define OFF_XFT   167488                   // xfcT[64][3][64][4] = 49152 -> 216640

#define RECH_N 9216
#define TAIL_N 59392                       // 9216 + 1024 + 49152 = 232 blocks

#define RPAD 36
#define NROW 100

// ---------------- per-block weight-row staging (coalesced) ----------------
__device__ __forceinline__ void stage_wrow(
    const float* __restrict__ wmid, int m, int f, int tid, f16* wrow)
{
  const float* src = wmid + m * 196608 + f * 3072 + tid * 12;
  f16* dst = wrow + (tid >> 3) * 100 + (tid & 7) * 12;   // no row crossing
#pragma unroll
  for (int u = 0; u < 3; ++u) {
    const float4 v = *reinterpret_cast<const float4*>(src + u * 4);
    dst[u * 4 + 0] = (f16)v.x; dst[u * 4 + 1] = (f16)v.y;
    dst[u * 4 + 2] = (f16)v.z; dst[u * 4 + 3] = (f16)v.w;
  }
}

// ---------------- MFMA tile; fragments built from LDS wrow ----------------
__device__ __forceinline__ void mfma_tile2(
    const f16* IN, f16* OUT, int d, int base,
    const f16* __restrict__ wrow, int lane, const float* sBias)
{
  const int lg = lane >> 5;
  const int co = lane & 31;
  const int col = base + co;

  f16x8 afr[6];
#pragma unroll
  for (int h = 0; h < 2; ++h) {
    const f16* wp = wrow + co * 100 + (h * 16 + lg * 8) * 3;
    f16x4 w4[6];
#pragma unroll
    for (int u = 0; u < 6; ++u) w4[u] = *(const f16x4*)(wp + u * 4);
#pragma unroll
    for (int t = 0; t < 3; ++t)
#pragma unroll
      for (int j = 0; j < 8; ++j) {
        const int o = 3 * j + t;
        afr[t * 2 + h][j] = w4[o >> 2][o & 3];
      }
  }

  f32x16 acc;
#pragma unroll
  for (int r = 0; r < 16; ++r)
    acc[r] = sBias[(r & 3) + 8 * (r >> 2) + 4 * lg];

#pragma unroll
  for (int t = 0; t < 3; ++t) {
#pragma unroll
    for (int h = 0; h < 2; ++h) {
      const f16* bp = IN + (col + t * d) * RPAD + h * 16 + lg * 8;
      f16x4 lo = *(const f16x4*)bp;
      f16x4 hi = *(const f16x4*)(bp + 4);
      f16x8 b = __builtin_shufflevector(lo, hi, 0, 1, 2, 3, 4, 5, 6, 7);
      acc = __builtin_amdgcn_mfma_f32_32x32x16_f16(afr[t * 2 + h], b, acc, 0, 0, 0);
    }
  }

#pragma unroll
  for (int q = 0; q < 4; ++q) {
    const int co0 = q * 8 + 4 * lg;
    f16x4 w;
#pragma unroll
    for (int e = 0; e < 4; ++e)
      w[e] = (f16)fmaxf(acc[q * 4 + e], 0.f);
    *(f16x4*)(OUT + col * RPAD + co0) = w;
  }
}

// ---------------- kernel A: precompute + table tail (R13) ----------------
__global__ __launch_bounds__(256) void tcn_pre(
    const float* __restrict__ x, const float* __restrict__ xfc,
    const float* __restrict__ w0, const float* __restrict__ b0,
    const float* __restrict__ wmid, const float* __restrict__ bmid,
    const float* __restrict__ wlast, const float* __restrict__ blast,
    const float* __restrict__ linW, const float* __restrict__ linb,
    float* __restrict__ ws)
{
  const int blk = blockIdx.x;
  const int tid = threadIdx.x;

  if (blk >= 4096) {   // ---- table-builder tail blocks ----
    const int idx = (blk - 4096) * 256 + tid;
    if (idx < RECH_N) {
      const int e = idx & 7, lane = (idx >> 3) & 63, q = idx >> 9;
      const int i = q * 8 + e;
      const int m = i / 48, r2 = i % 48;
      const int k = r2 >> 4, ci = r2 & 15;
      const int c = lane & 31, cib = (lane >> 5) * 16;
      ((f16*)(ws + OFF_RECH))[idx] =
          (f16)wmid[m * 196608 + (2016 + c) * 96 + (cib + ci) * 3 + k];
    } else if (idx < RECH_N + 1024) {
      const int r = idx - RECH_N;
      const int e = r & 3, lane = (r >> 2) & 63, q = r >> 8;
      const int i = q * 4 + e;
      const int c = lane & 31;
      float v = 0.f;
      if (i < 3)        v = w0[(2016 + c) * 3 + i];
      else if (i == 3)  v = b0[2016 + c];
      else if (i < 7)   v = bmid[(i - 4) * 2048 + 2016 + c];
      else if (i < 10)  v = wlast[63 * 96 + c * 3 + (i - 7)];
      else if (i == 10) v = blast[63];
      else if (i == 11) v = linW[63];
      else if (i == 12) v = linb[0];
      ws[OFF_PRM + r] = v;
    } else if (idx < TAIL_N) {
      const int r = idx - (RECH_N + 1024);
      const int b = r / 768, rem = r % 768;
      const int q = rem >> 8, lane = (rem >> 2) & 63, e = rem & 3;
      const int i = q * 4 + e;
      ws[OFF_XFT + r] = (lane < 63 && i < 12) ? xfc[(b * 12 + i) * 63 + lane] : 0.f;
    }
    return;
  }

  const int b = blk >> 6;
  const int f = blk & 63;
  const bool lastf = (f == 63);
  const int lane = tid & 63;
  const int g = __builtin_amdgcn_readfirstlane(tid >> 6);

  __shared__ float sIn[80];
  __shared__ float sBias[3][32];
  __shared__ f16 actA[NROW * RPAD];
  __shared__ f16 actB[NROW * RPAD];
  __shared__ __align__(8) f16 wrow[32 * 100];

  for (int t = tid; t < 80; t += 256) {
    float v = 0.f;
    if (t < 63)                 v = x[(b * 63 + t) * 64 + f];
    else if (t < 74 && !lastf)  v = xfc[(b * 12 + (t - 63)) * 63 + f];
    sIn[t] = v;
  }
  if (tid < 96) sBias[tid >> 5][tid & 31] = bmid[(tid >> 5) * 2048 + f * 32 + (tid & 31)];
  for (int i = tid; i < (NROW - 72) * RPAD; i += 256) actA[72 * RPAD + i] = (f16)0.f;
  for (int i = tid; i < (NROW - 68) * RPAD; i += 256) actB[68 * RPAD + i] = (f16)0.f;
  stage_wrow(wmid, 0, f, tid, wrow);
  __syncthreads();

  // ---- L0 (d=1, 1->32ch), pos 0..71 -> actA ----
  {
    const float* wb  = w0 + (f * 32 + g * 8) * 3;
    const float* bbp = b0 + f * 32 + g * 8;
#pragma unroll
    for (int it = 0; it < 2; ++it) {
      const int p = lane + it * 64;
      if (p < 72) {
        const float i0 = sIn[p], i1 = sIn[p + 1], i2 = sIn[p + 2];
        f16x4 wv[2];
#pragma unroll
        for (int j = 0; j < 8; ++j) {
          float v = fmaf(wb[j * 3 + 0], i0,
                    fmaf(wb[j * 3 + 1], i1,
                    fmaf(wb[j * 3 + 2], i2, bbp[j])));
          wv[j >> 2][j & 3] = (f16)fmaxf(v, 0.f);
        }
        *(f16x4*)(actA + p * RPAD + g * 8)     = wv[0];
        *(f16x4*)(actA + p * RPAD + g * 8 + 4) = wv[1];
      }
    }
  }
  __syncthreads();

  float* st = ws + OFF_ST + b * ST_STRIDE;

  // ---- mfma L1 (d=2) ----
  if (lastf) {
    for (int t = tid; t < 128; t += 256)
      st[ST_L0 + t] = (float)actA[(57 + (t >> 5)) * RPAD + (t & 31)];
  }
  if (g < 3) mfma_tile2(actA, actB, 2, g * 32, wrow, lane, sBias[0]);
  __syncthreads();

  stage_wrow(wmid, 1, f, tid, wrow);
  if (lastf) {
    for (int t = tid; t < 256; t += 256)
      st[ST_L1 + t] = (float)actB[(49 + (t >> 5)) * RPAD + (t & 31)];
  }
  __syncthreads();

  // ---- mfma L2 (d=4) ----
  if (g < 2) mfma_tile2(actB, actA, 4, g * 32, wrow, lane, sBias[1]);
  __syncthreads();

  stage_wrow(wmid, 2, f, tid, wrow);
  if (lastf) {
    for (int t = tid; t < 512; t += 256)
      st[ST_L2 + t] = (float)actA[(33 + (t >> 5)) * RPAD + (t & 31)];
  }
  __syncthreads();

  // ---- mfma L3 (d=8) ----
  if (g < 2) mfma_tile2(actA, actB, 8, g * 32, wrow, lane, sBias[2]);
  __syncthreads();

  // ---- L3 slice; L4 (d=16, 32->1, no relu) ----
  if (lastf) {
    for (int t = tid; t < 864; t += 256)
      st[ST_L3 + t] = (float)actB[(1 + (t >> 5)) * RPAD + (t & 31)];
  }
  if (tid < 12) {
    const int p = tid;
    float acc = blast[f];
    const float* wl = wlast + f * 96;
#pragma unroll
    for (int k = 0; k < 3; ++k) {
      const int row = p + 16 * k;
#pragma unroll
      for (int ci0 = 0; ci0 < 32; ci0 += 4) {
        f16x4 av = *(const f16x4*)(actB + row * RPAD + ci0);
#pragma unroll
        for (int e = 0; e < 4; ++e)
          acc = fmaf(wl[(ci0 + e) * 3 + k], (float)av[e], acc);
      }
    }
    if (!lastf) {
      ws[OFF_H4 + b * 768 + (p >> 2) * 256 + f * 4 + (p & 3)] = acc;
    } else {
      ws[OFF_H4 + b * 768 + (p >> 2) * 256 + 63 * 4 + (p & 3)] = 0.f;
      if (p == 0) ws[OFF_H40 + b] = acc;
    }
  }
}

// ---------------- kernel B: sequential feature-63 chain ----------------

__device__ __forceinline__ float fd2(h2 a, h2 b, float c) {
#if __has_builtin(__builtin_amdgcn_fdot2)
  return __builtin_amdgcn_fdot2(a, b, c, false);
#else
  return fmaf((float)a[0], (float)b[0], fmaf((float)a[1], (float)b[1], c));
#endif
}

__device__ __forceinline__ float dotv(f16x8 w, f16x8 a, float acc) {
  h2 w0 = {w[0], w[1]}, a0 = {a[0], a[1]};
  h2 w1 = {w[2], w[3]}, a1 = {a[2], a[3]};
  h2 w2 = {w[4], w[5]}, a2 = {a[4], a[5]};
  h2 w3 = {w[6], w[7]}, a3 = {a[6], a[7]};
  acc = fd2(w0, a0, acc);
  acc = fd2(w1, a1, acc);
  acc = fd2(w2, a2, acc);
  acc = fd2(w3, a3, acc);
  return acc;
}

__device__ __forceinline__ f16x8 combineh(f16x8 lo, f16x8 hi) {
  f16x8 s = lo + hi;
#pragma unroll
  for (int i = 0; i < 8; ++i) s[i] = (s[i] > (f16)0.f) ? s[i] : (f16)0.f;
  return s;
}

__device__ __forceinline__ void load16f(const float* p, float* r) {
  const float4* q = reinterpret_cast<const float4*>(p);
  const float4 v0 = q[0], v1 = q[1], v2 = q[2], v3 = q[3];
  r[0]=v0.x;  r[1]=v0.y;  r[2]=v0.z;  r[3]=v0.w;
  r[4]=v1.x;  r[5]=v1.y;  r[6]=v1.z;  r[7]=v1.w;
  r[8]=v2.x;  r[9]=v2.y;  r[10]=v2.z; r[11]=v2.w;
  r[12]=v3.x; r[13]=v3.y; r[14]=v3.z; r[15]=v3.w;
}

__global__ __launch_bounds__(256, 1) void tcn_seq(
    const float* __restrict__ x,
    const float* __restrict__ linW,
    const float* __restrict__ ws, float* __restrict__ out)
{
  const int b = blockIdx.x;
  const int tid = threadIdx.x;
  const int wid = tid >> 6;
  const int lane = tid & 63;
  const int c = lane & 31;
  const int h = (lane >> 5) & 1;
  const int cib = h * 16;

  __shared__ __align__(16) f16 L0h[15 * 32];
  __shared__ __align__(16) f16 L1p[2][19 * 32];
  __shared__ __align__(16) f16 L2p[2][27 * 32];
  __shared__ __align__(16) f16 wseqh[18 * 64 * 8];
  __shared__ __align__(16) float qs[32];
  __shared__ float preArr[12];

  const float* stp = ws + OFF_ST + b * ST_STRIDE;

  // ---- waves 1-3: parallel staging, then exit ----
  if (wid == 1) {
    const f16* rech = (const f16*)(ws + OFF_RECH);
#pragma unroll
    for (int q = 0; q < 18; ++q)
      *(f16x8*)(wseqh + (q * 64 + lane) * 8) = *(const f16x8*)(rech + (q * 64 + lane) * 8);
  } else if (wid == 2) {
    for (int t = lane; t < 128; t += 64) L0h[t] = (f16)stp[ST_L0 + t];
    for (int t = lane; t < 256; t += 64) { L1p[0][t] = (f16)stp[ST_L1 + t]; L1p[1][t] = (f16)0.f; }
  } else if (wid == 3) {
    for (int t = lane; t < 512; t += 64) { L2p[0][t] = (f16)stp[ST_L2 + t]; L2p[1][t] = (f16)0.f; }
  }
  if (wid != 0) { __syncthreads(); return; }

  // ---- wave 0: params + accv ----
  float prm[16];
  {
    const float* tab = ws + OFF_PRM;
#pragma unroll
    for (int q = 0; q < 4; ++q) {
      const float4 v = *reinterpret_cast<const float4*>(tab + (q * 64 + lane) * 4);
      prm[q * 4 + 0] = v.x; prm[q * 4 + 1] = v.y;
      prm[q * 4 + 2] = v.z; prm[q * 4 + 3] = v.w;
    }
  }
  const float w00 = prm[0],  w01 = prm[1],  w02 = prm[2],  b00 = prm[3];
  const float bm0 = prm[4],  bm1 = prm[5],  bm2 = prm[6];
  const float wl0c = prm[7], wl1c = prm[8], wl2c = prm[9];
  const float bl = prm[10],  lw63 = prm[11], lb0 = prm[12];

  const float xv61 = x[(b * 63 + 61) * 64 + 63];
  const float xv62 = x[(b * 63 + 62) * 64 + 63];
  const float h40v = ws[OFF_H40 + b];

  float accv[12];
  {
    float lw = 0.f, lwx = 0.f;
    if (lane < 63) { lw = linW[lane]; lwx = linW[64 + lane]; }
    float h4v[12], xv[12];
#pragma unroll
    for (int q = 0; q < 3; ++q) {
      const float4 hv  = *reinterpret_cast<const float4*>(ws + OFF_H4 + b * 768 + q * 256 + lane * 4);
      const float4 xvv = *reinterpret_cast<const float4*>(ws + OFF_XFT + b * 768 + q * 256 + lane * 4);
      h4v[q*4+0] = hv.x; h4v[q*4+1] = hv.y; h4v[q*4+2] = hv.z; h4v[q*4+3] = hv.w;
      xv[q*4+0] = xvv.x; xv[q*4+1] = xvv.y; xv[q*4+2] = xvv.z; xv[q*4+3] = xvv.w;
    }
#pragma unroll
    for (int i = 0; i < 12; ++i) accv[i] = fmaf(lw, h4v[i], lwx * xv[i]);

    if (lane < 32) {   // fold L4 taps 0/1 (precomputed L3 rows, global reads)
#pragma unroll
      for (int i = 1; i < 12; ++i) {
        const float qc = fmaf(wl0c, stp[ST_L3 + (i - 1) * 32 + lane],
                              wl1c * stp[ST_L3 + (i + 15) * 32 + lane]);
        accv[i] = fmaf(lw63, qc, accv[i]);
      }
    }
#pragma unroll
    for (int r = 1; r < 64; r <<= 1) {
#pragma unroll
      for (int i = 0; i < 12; ++i) accv[i] += __shfl_xor(accv[i], r);
    }
  }
  if (lane == 0) {
#pragma unroll
    for (int i = 1; i < 12; ++i) preArr[i] = accv[i] + lb0 + lw63 * bl;
  }
  __syncthreads();   // pairs with waves 1-3's barrier; staging visible

  // opaque pointer: keep per-iteration wseqh reads (no LICM re-hoist)
  const f16* wbase = wseqh;
  asm volatile("" : "+v"(wbase));

  // ---- step 0 ----
  const float out0 = fmaf(lw63, h40v, accv[0] + lb0);
  if (lane == 0) out[b * 12 + 0] = out0;
  float o1 = out0, o2 = xv62, o3 = xv61;

  // ---- steps 1..11 (rolled; f16 data, f32 accum) ----
#pragma unroll 1
  for (int s = 1; s < 12; ++s) {
    const float preS = preArr[s];

    const float nL0 = fmaxf(fmaf(w00, o3, fmaf(w01, o2, fmaf(w02, o1, b00))), 0.f);
    L0h[(3 + s) * 32 + c] = (f16)nL0;

    // ---- L1 @ 56+s ----
    float v1;
    {
      const f16* wp = wbase + (0 * 6 * 64 + lane) * 8;
      f16x8 W0 = *(const f16x8*)(wp);
      f16x8 W1 = *(const f16x8*)(wp + 64 * 8);
      f16x8 W2 = *(const f16x8*)(wp + 2 * 64 * 8);
      f16x8 W3 = *(const f16x8*)(wp + 3 * 64 * 8);
      f16x8 W4 = *(const f16x8*)(wp + 4 * 64 * 8);
      f16x8 W5 = *(const f16x8*)(wp + 5 * 64 * 8);
      const f16* r0p = L0h + (s - 1) * 32 + cib;
      const f16* r1p = L0h + (s + 1) * 32 + cib;
      const f16* np  = L0h + (3 + s) * 32 + cib;
      f16x8 R0a = *(const f16x8*)r0p, R0b = *(const f16x8*)(r0p + 8);
      f16x8 R1a = *(const f16x8*)r1p, R1b = *(const f16x8*)(r1p + 8);
      f16x8 Na  = *(const f16x8*)np,  Nb  = *(const f16x8*)(np + 8);
      float a0 = dotv(W0, R0a, 0.f), a1 = dotv(W1, R0b, 0.f);
      a0 = dotv(W2, R1a, a0);        a1 = dotv(W3, R1b, a1);
      a0 = dotv(W4, Na, a0);         a1 = dotv(W5, Nb, a1);
      v1 = a0 + a1 + (h == 0 ? bm0 : 0.f);
    }
    L1p[h][(7 + s) * 32 + c] = (f16)v1;

    // ---- L2 @ 48+s ----
    float v2;
    {
      const f16* wp = wbase + (1 * 6 * 64 + lane) * 8;
      f16x8 W0 = *(const f16x8*)(wp);
      f16x8 W1 = *(const f16x8*)(wp + 64 * 8);
      f16x8 W2 = *(const f16x8*)(wp + 2 * 64 * 8);
      f16x8 W3 = *(const f16x8*)(wp + 3 * 64 * 8);
      f16x8 W4 = *(const f16x8*)(wp + 4 * 64 * 8);
      f16x8 W5 = *(const f16x8*)(wp + 5 * 64 * 8);
      const int i0 = (s - 1) * 32 + cib, i1 = (s + 3) * 32 + cib, in = (7 + s) * 32 + cib;
      f16x8 R0a = combineh(*(const f16x8*)(&L1p[0][i0]),     *(const f16x8*)(&L1p[1][i0]));
      f16x8 R0b = combineh(*(const f16x8*)(&L1p[0][i0 + 8]), *(const f16x8*)(&L1p[1][i0 + 8]));
      f16x8 R1a = combineh(*(const f16x8*)(&L1p[0][i1]),     *(const f16x8*)(&L1p[1][i1]));
      f16x8 R1b = combineh(*(const f16x8*)(&L1p[0][i1 + 8]), *(const f16x8*)(&L1p[1][i1 + 8]));
      f16x8 Na  = combineh(*(const f16x8*)(&L1p[0][in]),     *(const f16x8*)(&L1p[1][in]));
      f16x8 Nb  = combineh(*(const f16x8*)(&L1p[0][in + 8]), *(const f16x8*)(&L1p[1][in + 8]));
      float a0 = dotv(W0, R0a, 0.f), a1 = dotv(W1, R0b, 0.f);
      a0 = dotv(W2, R1a, a0);        a1 = dotv(W3, R1b, a1);
      a0 = dotv(W4, Na, a0);         a1 = dotv(W5, Nb, a1);
      v2 = a0 + a1 + (h == 0 ? bm1 : 0.f);
    }
    L2p[h][(15 + s) * 32 + c] = (f16)v2;

    // ---- L3 @ 32+s ----
    float v3;
    {
      const f16* wp = wbase + (2 * 6 * 64 + lane) * 8;
      f16x8 W0 = *(const f16x8*)(wp);
      f16x8 W1 = *(const f16x8*)(wp + 64 * 8);
      f16x8 W2 = *(const f16x8*)(wp + 2 * 64 * 8);
      f16x8 W3 = *(const f16x8*)(wp + 3 * 64 * 8);
      f16x8 W4 = *(const f16x8*)(wp + 4 * 64 * 8);
      f16x8 W5 = *(const f16x8*)(wp + 5 * 64 * 8);
      const int i0 = (s - 1) * 32 + cib, i1 = (s + 7) * 32 + cib, in = (15 + s) * 32 + cib;
      f16x8 R0a = combineh(*(const f16x8*)(&L2p[0][i0]),     *(const f16x8*)(&L2p[1][i0]));
      f16x8 R0b = combineh(*(const f16x8*)(&L2p[0][i0 + 8]), *(const f16x8*)(&L2p[1][i0 + 8]));
      f16x8 R1a = combineh(*(const f16x8*)(&L2p[0][i1]),     *(const f16x8*)(&L2p[1][i1]));
      f16x8 R1b = combineh(*(const f16x8*)(&L2p[0][i1 + 8]), *(const f16x8*)(&L2p[1][i1 + 8]));
      f16x8 Na  = combineh(*(const f16x8*)(&L2p[0][in]),     *(const f16x8*)(&L2p[1][in]));
      f16x8 Nb  = combineh(*(const f16x8*)(&L2p[0][in + 8]), *(const f16x8*)(&L2p[1][in + 8]));
      float a0 = dotv(W0, R0a, 0.f), a1 = dotv(W1, R0b, 0.f);
      a0 = dotv(W2, R1a, a0);        a1 = dotv(W3, R1b, a1);
      a0 = dotv(W4, Na, a0);         a1 = dotv(W5, Nb, a1);
      v3 = a0 + a1 + (h == 0 ? bm2 : 0.f);
    }
    v3 += __shfl_xor(v3, 32);
    const float nL3 = fmaxf(v3, 0.f);

    // ---- L4 @ s: tap2 only; sum over co via LDS broadcast roundtrip ----
    if (h == 0) qs[c] = wl2c * nL3;
    float qa[16], qb[16];
    load16f(qs, qa); load16f(qs + 16, qb);
    float s0 = 0.f, s1 = 0.f, s2 = 0.f, s3 = 0.f;
#pragma unroll
    for (int i = 0; i < 16; i += 4) {
      s0 += qa[i + 0] + qb[i + 0];
      s1 += qa[i + 1] + qb[i + 1];
      s2 += qa[i + 2] + qb[i + 2];
      s3 += qa[i + 3] + qb[i + 3];
    }
    const float S = (s0 + s1) + (s2 + s3);
    const float outs = fmaf(lw63, S, preS);
    if (lane == 0) out[b * 12 + s] = outs;
    o3 = o2; o2 = o1; o1 = outs;
  }
}

// ---------------- launcher ----------------

extern "C" void kernel_launch(void* const* d_in, const int* in_sizes, int n_in,
                              void* d_out, int out_size, void* d_ws, size_t ws_size,
                              hipStream_t stream) {
  const float* x     = (const float*)d_in[0];
  const float* xfc   = (const float*)d_in[1];
  const float* w0    = (const float*)d_in[2];
  const float* b0    = (const float*)d_in[3];
  const float* wmid  = (const float*)d_in[4];
  const float* bmid  = (const float*)d_in[5];
  const float* wlast = (const float*)d_in[6];
  const float* blast = (const float*)d_in[7];
  const float* linW  = (const float*)d_in[8];
  const float* linb  = (const float*)d_in[9];
  float* out = (float*)d_out;
  float* ws  = (float*)d_ws;

  // 4096 compute blocks + 232 table tail blocks
  tcn_pre<<<4096 + 232, 256, 0, stream>>>(
      x, xfc, w0, b0, wmid, bmid, wlast, blast, linW, linb, ws);
  tcn_seq<<<64, 256, 0, stream>>>(x, linW, ws, out);
}

// Round 17
// 37.154 us; speedup vs baseline: 4.0913x; 1.0260x over previous
//
#include <hip/hip_runtime.h>

// B=64, S=63, F=64, T=12, NF=63, OUT=1, C=32, K=3, DILS=(1,2,4,8,16)
//
// R17 = R16 + pre tile-shift: overlapping MFMA tile bases (L1:{0,32,36},
// L2:{0,28}, L3:{0,12}) cover exactly the valid positions -> no garbage
// reads, no zero-fill, act buffers [72][36], LDS 21504->17472 (9 blk/CU).
//  tcn_seq: R16 form (4-wave parallel setup; wave 0 runs f16 chain).

typedef _Float16 f16;
typedef _Float16 h2 __attribute__((ext_vector_type(2)));
typedef _Float16 f16x4 __attribute__((ext_vector_type(4)));
typedef _Float16 f16x8 __attribute__((ext_vector_type(8)));
typedef float f32x16 __attribute__((ext_vector_type(16)));

// ---------------- workspace layout (float offsets) ----------------
#define OFF_H4    0                        // h4T [64][3][64][4] = 49152
#define OFF_ST    49152                    // feature-63 state, per-b stride 1760
#define ST_L0     0                        // L0 pos 57..60   (4*32)  [pos][ch]
#define ST_L1     128                      // L1 pos 49..56   (8*32)
#define ST_L2     384                      // L2 pos 33..48   (16*32)
#define ST_L3     896                      // L3 pos 1..27    (27*32)
#define ST_STRIDE 1760                     // ends 161792
#define OFF_H40   161792                   // [64]
#define OFF_RECH  161856                   // f16 rech[18][64][8] = 9216 f16 = 4608 fl
#define OFF_PRM   166464                   // prm[4][64][4] f32 = 1024
#define OFF_XFT   167488                   // xfcT[64][3][64][4] = 49152 -> 216640

#define RECH_N 9216
#define TAIL_N 59392                       // 9216 + 1024 + 49152 = 232 blocks

#define RPAD 36
#define NROW 72

// ---------------- per-block weight-row staging (coalesced) ----------------
__device__ __forceinline__ void stage_wrow(
    const float* __restrict__ wmid, int m, int f, int tid, f16* wrow)
{
  const float* src = wmid + m * 196608 + f * 3072 + tid * 12;
  f16* dst = wrow + (tid >> 3) * 100 + (tid & 7) * 12;   // no row crossing
#pragma unroll
  for (int u = 0; u < 3; ++u) {
    const float4 v = *reinterpret_cast<const float4*>(src + u * 4);
    dst[u * 4 + 0] = (f16)v.x; dst[u * 4 + 1] = (f16)v.y;
    dst[u * 4 + 2] = (f16)v.z; dst[u * 4 + 3] = (f16)v.w;
  }
}

// ---------------- MFMA tile; fragments built from LDS wrow ----------------
// Overlapping tile bases: duplicate computations are bit-identical -> the
// write-write overlap in OUT is a benign race.
__device__ __forceinline__ void mfma_tile2(
    const f16* IN, f16* OUT, int d, int base,
    const f16* __restrict__ wrow, int lane, const float* sBias)
{
  const int lg = lane >> 5;
  const int co = lane & 31;
  const int col = base + co;

  f16x8 afr[6];
#pragma unroll
  for (int h = 0; h < 2; ++h) {
    const f16* wp = wrow + co * 100 + (h * 16 + lg * 8) * 3;
    f16x4 w4[6];
#pragma unroll
    for (int u = 0; u < 6; ++u) w4[u] = *(const f16x4*)(wp + u * 4);
#pragma unroll
    for (int t = 0; t < 3; ++t)
#pragma unroll
      for (int j = 0; j < 8; ++j) {
        const int o = 3 * j + t;
        afr[t * 2 + h][j] = w4[o >> 2][o & 3];
      }
  }

  f32x16 acc;
#pragma unroll
  for (int r = 0; r < 16; ++r)
    acc[r] = sBias[(r & 3) + 8 * (r >> 2) + 4 * lg];

#pragma unroll
  for (int t = 0; t < 3; ++t) {
#pragma unroll
    for (int h = 0; h < 2; ++h) {
      const f16* bp = IN + (col + t * d) * RPAD + h * 16 + lg * 8;
      f16x4 lo = *(const f16x4*)bp;
      f16x4 hi = *(const f16x4*)(bp + 4);
      f16x8 b = __builtin_shufflevector(lo, hi, 0, 1, 2, 3, 4, 5, 6, 7);
      acc = __builtin_amdgcn_mfma_f32_32x32x16_f16(afr[t * 2 + h], b, acc, 0, 0, 0);
    }
  }

#pragma unroll
  for (int q = 0; q < 4; ++q) {
    const int co0 = q * 8 + 4 * lg;
    f16x4 w;
#pragma unroll
    for (int e = 0; e < 4; ++e)
      w[e] = (f16)fmaxf(acc[q * 4 + e], 0.f);
    *(f16x4*)(OUT + col * RPAD + co0) = w;
  }
}

// ---------------- kernel A: precompute + table tail ----------------
__global__ __launch_bounds__(256) void tcn_pre(
    const float* __restrict__ x, const float* __restrict__ xfc,
    const float* __restrict__ w0, const float* __restrict__ b0,
    const float* __restrict__ wmid, const float* __restrict__ bmid,
    const float* __restrict__ wlast, const float* __restrict__ blast,
    const float* __restrict__ linW, const float* __restrict__ linb,
    float* __restrict__ ws)
{
  const int blk = blockIdx.x;
  const int tid = threadIdx.x;

  if (blk >= 4096) {   // ---- table-builder tail blocks ----
    const int idx = (blk - 4096) * 256 + tid;
    if (idx < RECH_N) {
      const int e = idx & 7, lane = (idx >> 3) & 63, q = idx >> 9;
      const int i = q * 8 + e;
      const int m = i / 48, r2 = i % 48;
      const int k = r2 >> 4, ci = r2 & 15;
      const int c = lane & 31, cib = (lane >> 5) * 16;
      ((f16*)(ws + OFF_RECH))[idx] =
          (f16)wmid[m * 196608 + (2016 + c) * 96 + (cib + ci) * 3 + k];
    } else if (idx < RECH_N + 1024) {
      const int r = idx - RECH_N;
      const int e = r & 3, lane = (r >> 2) & 63, q = r >> 8;
      const int i = q * 4 + e;
      const int c = lane & 31;
      float v = 0.f;
      if (i < 3)        v = w0[(2016 + c) * 3 + i];
      else if (i == 3)  v = b0[2016 + c];
      else if (i < 7)   v = bmid[(i - 4) * 2048 + 2016 + c];
      else if (i < 10)  v = wlast[63 * 96 + c * 3 + (i - 7)];
      else if (i == 10) v = blast[63];
      else if (i == 11) v = linW[63];
      else if (i == 12) v = linb[0];
      ws[OFF_PRM + r] = v;
    } else if (idx < TAIL_N) {
      const int r = idx - (RECH_N + 1024);
      const int b = r / 768, rem = r % 768;
      const int q = rem >> 8, lane = (rem >> 2) & 63, e = rem & 3;
      const int i = q * 4 + e;
      ws[OFF_XFT + r] = (lane < 63 && i < 12) ? xfc[(b * 12 + i) * 63 + lane] : 0.f;
    }
    return;
  }

  const int b = blk >> 6;
  const int f = blk & 63;
  const bool lastf = (f == 63);
  const int lane = tid & 63;
  const int g = __builtin_amdgcn_readfirstlane(tid >> 6);

  __shared__ float sIn[80];
  __shared__ float sBias[3][32];
  __shared__ f16 actA[NROW * RPAD];   // rows 0..71
  __shared__ f16 actB[NROW * RPAD];
  __shared__ __align__(8) f16 wrow[32 * 100];

  for (int t = tid; t < 80; t += 256) {
    float v = 0.f;
    if (t < 63)                 v = x[(b * 63 + t) * 64 + f];
    else if (t < 74 && !lastf)  v = xfc[(b * 12 + (t - 63)) * 63 + f];
    sIn[t] = v;
  }
  if (tid < 96) sBias[tid >> 5][tid & 31] = bmid[(tid >> 5) * 2048 + f * 32 + (tid & 31)];
  stage_wrow(wmid, 0, f, tid, wrow);
  __syncthreads();

  // ---- L0 (d=1, 1->32ch), pos 0..71 -> actA ----
  {
    const float* wb  = w0 + (f * 32 + g * 8) * 3;
    const float* bbp = b0 + f * 32 + g * 8;
#pragma unroll
    for (int it = 0; it < 2; ++it) {
      const int p = lane + it * 64;
      if (p < 72) {
        const float i0 = sIn[p], i1 = sIn[p + 1], i2 = sIn[p + 2];
        f16x4 wv[2];
#pragma unroll
        for (int j = 0; j < 8; ++j) {
          float v = fmaf(wb[j * 3 + 0], i0,
                    fmaf(wb[j * 3 + 1], i1,
                    fmaf(wb[j * 3 + 2], i2, bbp[j])));
          wv[j >> 2][j & 3] = (f16)fmaxf(v, 0.f);
        }
        *(f16x4*)(actA + p * RPAD + g * 8)     = wv[0];
        *(f16x4*)(actA + p * RPAD + g * 8 + 4) = wv[1];
      }
    }
  }
  __syncthreads();

  float* st = ws + OFF_ST + b * ST_STRIDE;

  // ---- mfma L1 (d=2): valid pos 0..67, tiles {0,32,36}, reads rows <=71 ----
  if (lastf) {
    for (int t = tid; t < 128; t += 256)
      st[ST_L0 + t] = (float)actA[(57 + (t >> 5)) * RPAD + (t & 31)];
  }
  if (g < 3) mfma_tile2(actA, actB, 2, (g == 2) ? 36 : g * 32, wrow, lane, sBias[0]);
  __syncthreads();

  stage_wrow(wmid, 1, f, tid, wrow);
  if (lastf) {
    for (int t = tid; t < 256; t += 256)
      st[ST_L1 + t] = (float)actB[(49 + (t >> 5)) * RPAD + (t & 31)];
  }
  __syncthreads();

  // ---- mfma L2 (d=4): valid pos 0..59, tiles {0,28}, reads rows <=67 ----
  if (g < 2) mfma_tile2(actB, actA, 4, g * 28, wrow, lane, sBias[1]);
  __syncthreads();

  stage_wrow(wmid, 2, f, tid, wrow);
  if (lastf) {
    for (int t = tid; t < 512; t += 256)
      st[ST_L2 + t] = (float)actA[(33 + (t >> 5)) * RPAD + (t & 31)];
  }
  __syncthreads();

  // ---- mfma L3 (d=8): valid pos 0..43, tiles {0,12}, reads rows <=59 ----
  if (g < 2) mfma_tile2(actA, actB, 8, g * 12, wrow, lane, sBias[2]);
  __syncthreads();

  // ---- L3 slice; L4 (d=16, 32->1, no relu), reads rows <=43 ----
  if (lastf) {
    for (int t = tid; t < 864; t += 256)
      st[ST_L3 + t] = (float)actB[(1 + (t >> 5)) * RPAD + (t & 31)];
  }
  if (tid < 12) {
    const int p = tid;
    float acc = blast[f];
    const float* wl = wlast + f * 96;
#pragma unroll
    for (int k = 0; k < 3; ++k) {
      const int row = p + 16 * k;
#pragma unroll
      for (int ci0 = 0; ci0 < 32; ci0 += 4) {
        f16x4 av = *(const f16x4*)(actB + row * RPAD + ci0);
#pragma unroll
        for (int e = 0; e < 4; ++e)
          acc = fmaf(wl[(ci0 + e) * 3 + k], (float)av[e], acc);
      }
    }
    if (!lastf) {
      ws[OFF_H4 + b * 768 + (p >> 2) * 256 + f * 4 + (p & 3)] = acc;
    } else {
      ws[OFF_H4 + b * 768 + (p >> 2) * 256 + 63 * 4 + (p & 3)] = 0.f;
      if (p == 0) ws[OFF_H40 + b] = acc;
    }
  }
}

// ---------------- kernel B: sequential feature-63 chain (R16) --------------

__device__ __forceinline__ float fd2(h2 a, h2 b, float c) {
#if __has_builtin(__builtin_amdgcn_fdot2)
  return __builtin_amdgcn_fdot2(a, b, c, false);
#else
  return fmaf((float)a[0], (float)b[0], fmaf((float)a[1], (float)b[1], c));
#endif
}

__device__ __forceinline__ float dotv(f16x8 w, f16x8 a, float acc) {
  h2 w0 = {w[0], w[1]}, a0 = {a[0], a[1]};
  h2 w1 = {w[2], w[3]}, a1 = {a[2], a[3]};
  h2 w2 = {w[4], w[5]}, a2 = {a[4], a[5]};
  h2 w3 = {w[6], w[7]}, a3 = {a[6], a[7]};
  acc = fd2(w0, a0, acc);
  acc = fd2(w1, a1, acc);
  acc = fd2(w2, a2, acc);
  acc = fd2(w3, a3, acc);
  return acc;
}

__device__ __forceinline__ f16x8 combineh(f16x8 lo, f16x8 hi) {
  f16x8 s = lo + hi;
#pragma unroll
  for (int i = 0; i < 8; ++i) s[i] = (s[i] > (f16)0.f) ? s[i] : (f16)0.f;
  return s;
}

__device__ __forceinline__ void load16f(const float* p, float* r) {
  const float4* q = reinterpret_cast<const float4*>(p);
  const float4 v0 = q[0], v1 = q[1], v2 = q[2], v3 = q[3];
  r[0]=v0.x;  r[1]=v0.y;  r[2]=v0.z;  r[3]=v0.w;
  r[4]=v1.x;  r[5]=v1.y;  r[6]=v1.z;  r[7]=v1.w;
  r[8]=v2.x;  r[9]=v2.y;  r[10]=v2.z; r[11]=v2.w;
  r[12]=v3.x; r[13]=v3.y; r[14]=v3.z; r[15]=v3.w;
}

__global__ __launch_bounds__(256, 1) void tcn_seq(
    const float* __restrict__ x,
    const float* __restrict__ linW,
    const float* __restrict__ ws, float* __restrict__ out)
{
  const int b = blockIdx.x;
  const int tid = threadIdx.x;
  const int wid = tid >> 6;
  const int lane = tid & 63;
  const int c = lane & 31;
  const int h = (lane >> 5) & 1;
  const int cib = h * 16;

  __shared__ __align__(16) f16 L0h[15 * 32];
  __shared__ __align__(16) f16 L1p[2][19 * 32];
  __shared__ __align__(16) f16 L2p[2][27 * 32];
  __shared__ __align__(16) f16 wseqh[18 * 64 * 8];
  __shared__ __align__(16) float qs[32];
  __shared__ float preArr[12];

  const float* stp = ws + OFF_ST + b * ST_STRIDE;

  // ---- waves 1-3: parallel staging, then exit ----
  if (wid == 1) {
    const f16* rech = (const f16*)(ws + OFF_RECH);
#pragma unroll
    for (int q = 0; q < 18; ++q)
      *(f16x8*)(wseqh + (q * 64 + lane) * 8) = *(const f16x8*)(rech + (q * 64 + lane) * 8);
  } else if (wid == 2) {
    for (int t = lane; t < 128; t += 64) L0h[t] = (f16)stp[ST_L0 + t];
    for (int t = lane; t < 256; t += 64) { L1p[0][t] = (f16)stp[ST_L1 + t]; L1p[1][t] = (f16)0.f; }
  } else if (wid == 3) {
    for (int t = lane; t < 512; t += 64) { L2p[0][t] = (f16)stp[ST_L2 + t]; L2p[1][t] = (f16)0.f; }
  }
  if (wid != 0) { __syncthreads(); return; }

  // ---- wave 0: params + accv ----
  float prm[16];
  {
    const float* tab = ws + OFF_PRM;
#pragma unroll
    for (int q = 0; q < 4; ++q) {
      const float4 v = *reinterpret_cast<const float4*>(tab + (q * 64 + lane) * 4);
      prm[q * 4 + 0] = v.x; prm[q * 4 + 1] = v.y;
      prm[q * 4 + 2] = v.z; prm[q * 4 + 3] = v.w;
    }
  }
  const float w00 = prm[0],  w01 = prm[1],  w02 = prm[2],  b00 = prm[3];
  const float bm0 = prm[4],  bm1 = prm[5],  bm2 = prm[6];
  const float wl0c = prm[7], wl1c = prm[8], wl2c = prm[9];
  const float bl = prm[10],  lw63 = prm[11], lb0 = prm[12];

  const float xv61 = x[(b * 63 + 61) * 64 + 63];
  const float xv62 = x[(b * 63 + 62) * 64 + 63];
  const float h40v = ws[OFF_H40 + b];

  float accv[12];
  {
    float lw = 0.f, lwx = 0.f;
    if (lane < 63) { lw = linW[lane]; lwx = linW[64 + lane]; }
    float h4v[12], xv[12];
#pragma unroll
    for (int q = 0; q < 3; ++q) {
      const float4 hv  = *reinterpret_cast<const float4*>(ws + OFF_H4 + b * 768 + q * 256 + lane * 4);
      const float4 xvv = *reinterpret_cast<const float4*>(ws + OFF_XFT + b * 768 + q * 256 + lane * 4);
      h4v[q*4+0] = hv.x; h4v[q*4+1] = hv.y; h4v[q*4+2] = hv.z; h4v[q*4+3] = hv.w;
      xv[q*4+0] = xvv.x; xv[q*4+1] = xvv.y; xv[q*4+2] = xvv.z; xv[q*4+3] = xvv.w;
    }
#pragma unroll
    for (int i = 0; i < 12; ++i) accv[i] = fmaf(lw, h4v[i], lwx * xv[i]);

    if (lane < 32) {
#pragma unroll
      for (int i = 1; i < 12; ++i) {
        const float qc = fmaf(wl0c, stp[ST_L3 + (i - 1) * 32 + lane],
                              wl1c * stp[ST_L3 + (i + 15) * 32 + lane]);
        accv[i] = fmaf(lw63, qc, accv[i]);
      }
    }
#pragma unroll
    for (int r = 1; r < 64; r <<= 1) {
#pragma unroll
      for (int i = 0; i < 12; ++i) accv[i] += __shfl_xor(accv[i], r);
    }
  }
  if (lane == 0) {
#pragma unroll
    for (int i = 1; i < 12; ++i) preArr[i] = accv[i] + lb0 + lw63 * bl;
  }
  __syncthreads();   // pairs with waves 1-3's barrier; staging visible

  // opaque pointer: keep per-iteration wseqh reads (no LICM re-hoist)
  const f16* wbase = wseqh;
  asm volatile("" : "+v"(wbase));

  // ---- step 0 ----
  const float out0 = fmaf(lw63, h40v, accv[0] + lb0);
  if (lane == 0) out[b * 12 + 0] = out0;
  float o1 = out0, o2 = xv62, o3 = xv61;

  // ---- steps 1..11 (rolled; f16 data, f32 accum) ----
#pragma unroll 1
  for (int s = 1; s < 12; ++s) {
    const float preS = preArr[s];

    const float nL0 = fmaxf(fmaf(w00, o3, fmaf(w01, o2, fmaf(w02, o1, b00))), 0.f);
    L0h[(3 + s) * 32 + c] = (f16)nL0;

    // ---- L1 @ 56+s ----
    float v1;
    {
      const f16* wp = wbase + (0 * 6 * 64 + lane) * 8;
      f16x8 W0 = *(const f16x8*)(wp);
      f16x8 W1 = *(const f16x8*)(wp + 64 * 8);
      f16x8 W2 = *(const f16x8*)(wp + 2 * 64 * 8);
      f16x8 W3 = *(const f16x8*)(wp + 3 * 64 * 8);
      f16x8 W4 = *(const f16x8*)(wp + 4 * 64 * 8);
      f16x8 W5 = *(const f16x8*)(wp + 5 * 64 * 8);
      const f16* r0p = L0h + (s - 1) * 32 + cib;
      const f16* r1p = L0h + (s + 1) * 32 + cib;
      const f16* np  = L0h + (3 + s) * 32 + cib;
      f16x8 R0a = *(const f16x8*)r0p, R0b = *(const f16x8*)(r0p + 8);
      f16x8 R1a = *(const f16x8*)r1p, R1b = *(const f16x8*)(r1p + 8);
      f16x8 Na  = *(const f16x8*)np,  Nb  = *(const f16x8*)(np + 8);
      float a0 = dotv(W0, R0a, 0.f), a1 = dotv(W1, R0b, 0.f);
      a0 = dotv(W2, R1a, a0);        a1 = dotv(W3, R1b, a1);
      a0 = dotv(W4, Na, a0);         a1 = dotv(W5, Nb, a1);
      v1 = a0 + a1 + (h == 0 ? bm0 : 0.f);
    }
    L1p[h][(7 + s) * 32 + c] = (f16)v1;

    // ---- L2 @ 48+s ----
    float v2;
    {
      const f16* wp = wbase + (1 * 6 * 64 + lane) * 8;
      f16x8 W0 = *(const f16x8*)(wp);
      f16x8 W1 = *(const f16x8*)(wp + 64 * 8);
      f16x8 W2 = *(const f16x8*)(wp + 2 * 64 * 8);
      f16x8 W3 = *(const f16x8*)(wp + 3 * 64 * 8);
      f16x8 W4 = *(const f16x8*)(wp + 4 * 64 * 8);
      f16x8 W5 = *(const f16x8*)(wp + 5 * 64 * 8);
      const int i0 = (s - 1) * 32 + cib, i1 = (s + 3) * 32 + cib, in = (7 + s) * 32 + cib;
      f16x8 R0a = combineh(*(const f16x8*)(&L1p[0][i0]),     *(const f16x8*)(&L1p[1][i0]));
      f16x8 R0b = combineh(*(const f16x8*)(&L1p[0][i0 + 8]), *(const f16x8*)(&L1p[1][i0 + 8]));
      f16x8 R1a = combineh(*(const f16x8*)(&L1p[0][i1]),     *(const f16x8*)(&L1p[1][i1]));
      f16x8 R1b = combineh(*(const f16x8*)(&L1p[0][i1 + 8]), *(const f16x8*)(&L1p[1][i1 + 8]));
      f16x8 Na  = combineh(*(const f16x8*)(&L1p[0][in]),     *(const f16x8*)(&L1p[1][in]));
      f16x8 Nb  = combineh(*(const f16x8*)(&L1p[0][in + 8]), *(const f16x8*)(&L1p[1][in + 8]));
      float a0 = dotv(W0, R0a, 0.f), a1 = dotv(W1, R0b, 0.f);
      a0 = dotv(W2, R1a, a0);        a1 = dotv(W3, R1b, a1);
      a0 = dotv(W4, Na, a0);         a1 = dotv(W5, Nb, a1);
      v2 = a0 + a1 + (h == 0 ? bm1 : 0.f);
    }
    L2p[h][(15 + s) * 32 + c] = (f16)v2;

    // ---- L3 @ 32+s ----
    float v3;
    {
      const f16* wp = wbase + (2 * 6 * 64 + lane) * 8;
      f16x8 W0 = *(const f16x8*)(wp);
      f16x8 W1 = *(const f16x8*)(wp + 64 * 8);
      f16x8 W2 = *(const f16x8*)(wp + 2 * 64 * 8);
      f16x8 W3 = *(const f16x8*)(wp + 3 * 64 * 8);
      f16x8 W4 = *(const f16x8*)(wp + 4 * 64 * 8);
      f16x8 W5 = *(const f16x8*)(wp + 5 * 64 * 8);
      const int i0 = (s - 1) * 32 + cib, i1 = (s + 7) * 32 + cib, in = (15 + s) * 32 + cib;
      f16x8 R0a = combineh(*(const f16x8*)(&L2p[0][i0]),     *(const f16x8*)(&L2p[1][i0]));
      f16x8 R0b = combineh(*(const f16x8*)(&L2p[0][i0 + 8]), *(const f16x8*)(&L2p[1][i0 + 8]));
      f16x8 R1a = combineh(*(const f16x8*)(&L2p[0][i1]),     *(const f16x8*)(&L2p[1][i1]));
      f16x8 R1b = combineh(*(const f16x8*)(&L2p[0][i1 + 8]), *(const f16x8*)(&L2p[1][i1 + 8]));
      f16x8 Na  = combineh(*(const f16x8*)(&L2p[0][in]),     *(const f16x8*)(&L2p[1][in]));
      f16x8 Nb  = combineh(*(const f16x8*)(&L2p[0][in + 8]), *(const f16x8*)(&L2p[1][in + 8]));
      float a0 = dotv(W0, R0a, 0.f), a1 = dotv(W1, R0b, 0.f);
      a0 = dotv(W2, R1a, a0);        a1 = dotv(W3, R1b, a1);
      a0 = dotv(W4, Na, a0);         a1 = dotv(W5, Nb, a1);
      v3 = a0 + a1 + (h == 0 ? bm2 : 0.f);
    }
    v3 += __shfl_xor(v3, 32);
    const float nL3 = fmaxf(v3, 0.f);

    // ---- L4 @ s: tap2 only; sum over co via LDS broadcast roundtrip ----
    if (h == 0) qs[c] = wl2c * nL3;
    float qa[16], qb[16];
    load16f(qs, qa); load16f(qs + 16, qb);
    float s0 = 0.f, s1 = 0.f, s2 = 0.f, s3 = 0.f;
#pragma unroll
    for (int i = 0; i < 16; i += 4) {
      s0 += qa[i + 0] + qb[i + 0];
      s1 += qa[i + 1] + qb[i + 1];
      s2 += qa[i + 2] + qb[i + 2];
      s3 += qa[i + 3] + qb[i + 3];
    }
    const float S = (s0 + s1) + (s2 + s3);
    const float outs = fmaf(lw63, S, preS);
    if (lane == 0) out[b * 12 + s] = outs;
    o3 = o2; o2 = o1; o1 = outs;
  }
}

// ---------------- launcher ----------------

extern "C" void kernel_launch(void* const* d_in, const int* in_sizes, int n_in,
                              void* d_out, int out_size, void* d_ws, size_t ws_size,
                              hipStream_t stream) {
  const float* x     = (const float*)d_in[0];
  const float* xfc   = (const float*)d_in[1];
  const float* w0    = (const float*)d_in[2];
  const float* b0    = (const float*)d_in[3];
  const float* wmid  = (const float*)d_in[4];
  const float* bmid  = (const float*)d_in[5];
  const float* wlast = (const float*)d_in[6];
  const float* blast = (const float*)d_in[7];
  const float* linW  = (const float*)d_in[8];
  const float* linb  = (const float*)d_in[9];
  float* out = (float*)d_out;
  float* ws  = (float*)d_ws;

  // 4096 compute blocks + 232 table tail blocks
  tcn_pre<<<4096 + 232, 256, 0, stream>>>(
      x, xfc, w0, b0, wmid, bmid, wlast, blast, linW, linb, ws);
  tcn_seq<<<64, 256, 0, stream>>>(x, linW, ws, out);
}

// Round 18
// 36.423 us; speedup vs baseline: 4.1733x; 1.0200x over previous
//
#include <hip/hip_runtime.h>

// B=64, S=63, F=64, T=12, NF=63, OUT=1, C=32, K=3, DILS=(1,2,4,8,16)
//
// R18 = R17 + batch-paired pre: 2048 compute blocks, each does batches
// {2bp, 2bp+1} for one feature f -> weight staging & phase overhead
// amortized x2; L2/L3 use all 4 waves. Tiles: L1 {0,32,36}, L2 {0,28},
// L3 {0,12} (overlap-benign). tcn_seq unchanged (R16 4-wave setup).

typedef _Float16 f16;
typedef _Float16 h2 __attribute__((ext_vector_type(2)));
typedef _Float16 f16x4 __attribute__((ext_vector_type(4)));
typedef _Float16 f16x8 __attribute__((ext_vector_type(8)));
typedef float f32x16 __attribute__((ext_vector_type(16)));

// ---------------- workspace layout (float offsets) ----------------
#define OFF_H4    0                        // h4T [64][3][64][4] = 49152
#define OFF_ST    49152                    // feature-63 state, per-b stride 1760
#define ST_L0     0                        // L0 pos 57..60   (4*32)  [pos][ch]
#define ST_L1     128                      // L1 pos 49..56   (8*32)
#define ST_L2     384                      // L2 pos 33..48   (16*32)
#define ST_L3     896                      // L3 pos 1..27    (27*32)
#define ST_STRIDE 1760                     // ends 161792
#define OFF_H40   161792                   // [64]
#define OFF_RECH  161856                   // f16 rech[18][64][8] = 9216 f16
#define OFF_PRM   166464                   // prm[4][64][4] f32 = 1024
#define OFF_XFT   167488                   // xfcT[64][3][64][4] = 49152 -> 216640

#define RECH_N 9216
#define TAIL_N 59392                       // 232 blocks
#define NCOMP  2048

#define RPAD 36
#define NROW 72
#define ASZ  (NROW * RPAD)                 // 2592 f16 per act buffer

// ---------------- per-block weight-row staging (coalesced) ----------------
__device__ __forceinline__ void stage_wrow(
    const float* __restrict__ wmid, int m, int f, int tid, f16* wrow)
{
  const float* src = wmid + m * 196608 + f * 3072 + tid * 12;
  f16* dst = wrow + (tid >> 3) * 100 + (tid & 7) * 12;   // no row crossing
#pragma unroll
  for (int u = 0; u < 3; ++u) {
    const float4 v = *reinterpret_cast<const float4*>(src + u * 4);
    dst[u * 4 + 0] = (f16)v.x; dst[u * 4 + 1] = (f16)v.y;
    dst[u * 4 + 2] = (f16)v.z; dst[u * 4 + 3] = (f16)v.w;
  }
}

// ---------------- MFMA tile; fragments built from LDS wrow ----------------
__device__ __forceinline__ void mfma_tile2(
    const f16* IN, f16* OUT, int d, int base,
    const f16* __restrict__ wrow, int lane, const float* sBias)
{
  const int lg = lane >> 5;
  const int co = lane & 31;
  const int col = base + co;

  f16x8 afr[6];
#pragma unroll
  for (int h = 0; h < 2; ++h) {
    const f16* wp = wrow + co * 100 + (h * 16 + lg * 8) * 3;
    f16x4 w4[6];
#pragma unroll
    for (int u = 0; u < 6; ++u) w4[u] = *(const f16x4*)(wp + u * 4);
#pragma unroll
    for (int t = 0; t < 3; ++t)
#pragma unroll
      for (int j = 0; j < 8; ++j) {
        const int o = 3 * j + t;
        afr[t * 2 + h][j] = w4[o >> 2][o & 3];
      }
  }

  f32x16 acc;
#pragma unroll
  for (int r = 0; r < 16; ++r)
    acc[r] = sBias[(r & 3) + 8 * (r >> 2) + 4 * lg];

#pragma unroll
  for (int t = 0; t < 3; ++t) {
#pragma unroll
    for (int h = 0; h < 2; ++h) {
      const f16* bp = IN + (col + t * d) * RPAD + h * 16 + lg * 8;
      f16x4 lo = *(const f16x4*)bp;
      f16x4 hi = *(const f16x4*)(bp + 4);
      f16x8 b = __builtin_shufflevector(lo, hi, 0, 1, 2, 3, 4, 5, 6, 7);
      acc = __builtin_amdgcn_mfma_f32_32x32x16_f16(afr[t * 2 + h], b, acc, 0, 0, 0);
    }
  }

#pragma unroll
  for (int q = 0; q < 4; ++q) {
    const int co0 = q * 8 + 4 * lg;
    f16x4 w;
#pragma unroll
    for (int e = 0; e < 4; ++e)
      w[e] = (f16)fmaxf(acc[q * 4 + e], 0.f);
    *(f16x4*)(OUT + col * RPAD + co0) = w;
  }
}

// ---------------- kernel A: precompute (batch-paired) + table tail --------
__global__ __launch_bounds__(256) void tcn_pre(
    const float* __restrict__ x, const float* __restrict__ xfc,
    const float* __restrict__ w0, const float* __restrict__ b0,
    const float* __restrict__ wmid, const float* __restrict__ bmid,
    const float* __restrict__ wlast, const float* __restrict__ blast,
    const float* __restrict__ linW, const float* __restrict__ linb,
    float* __restrict__ ws)
{
  const int blk = blockIdx.x;
  const int tid = threadIdx.x;

  if (blk >= NCOMP) {   // ---- table-builder tail blocks ----
    const int idx = (blk - NCOMP) * 256 + tid;
    if (idx < RECH_N) {
      const int e = idx & 7, lane = (idx >> 3) & 63, q = idx >> 9;
      const int i = q * 8 + e;
      const int m = i / 48, r2 = i % 48;
      const int k = r2 >> 4, ci = r2 & 15;
      const int c = lane & 31, cib = (lane >> 5) * 16;
      ((f16*)(ws + OFF_RECH))[idx] =
          (f16)wmid[m * 196608 + (2016 + c) * 96 + (cib + ci) * 3 + k];
    } else if (idx < RECH_N + 1024) {
      const int r = idx - RECH_N;
      const int e = r & 3, lane = (r >> 2) & 63, q = r >> 8;
      const int i = q * 4 + e;
      const int c = lane & 31;
      float v = 0.f;
      if (i < 3)        v = w0[(2016 + c) * 3 + i];
      else if (i == 3)  v = b0[2016 + c];
      else if (i < 7)   v = bmid[(i - 4) * 2048 + 2016 + c];
      else if (i < 10)  v = wlast[63 * 96 + c * 3 + (i - 7)];
      else if (i == 10) v = blast[63];
      else if (i == 11) v = linW[63];
      else if (i == 12) v = linb[0];
      ws[OFF_PRM + r] = v;
    } else if (idx < TAIL_N) {
      const int r = idx - (RECH_N + 1024);
      const int b = r / 768, rem = r % 768;
      const int q = rem >> 8, lane = (rem >> 2) & 63, e = rem & 3;
      const int i = q * 4 + e;
      ws[OFF_XFT + r] = (lane < 63 && i < 12) ? xfc[(b * 12 + i) * 63 + lane] : 0.f;
    }
    return;
  }

  const int bp = blk >> 6;          // batch pair 0..31
  const int f = blk & 63;
  const bool lastf = (f == 63);
  const int lane = tid & 63;
  const int g = __builtin_amdgcn_readfirstlane(tid >> 6);

  __shared__ float sIn[2][80];
  __shared__ float sBias[3][32];
  __shared__ f16 actA[2][ASZ];
  __shared__ f16 actB[2][ASZ];
  __shared__ __align__(8) f16 wrow[32 * 100];

  // ---- phase0: inputs (both batches), biases, stage layer-0 weights ----
  for (int t = tid; t < 160; t += 256) {
    const int q = t / 80, tt = t % 80;
    const int b = bp * 2 + q;
    float v = 0.f;
    if (tt < 63)                 v = x[(b * 63 + tt) * 64 + f];
    else if (tt < 74 && !lastf)  v = xfc[(b * 12 + (tt - 63)) * 63 + f];
    sIn[q][tt] = v;
  }
  if (tid < 96) sBias[tid >> 5][tid & 31] = bmid[(tid >> 5) * 2048 + f * 32 + (tid & 31)];
  stage_wrow(wmid, 0, f, tid, wrow);
  __syncthreads();

  // ---- phase1: L0 (d=1, 1->32ch), pos 0..71, both batches ----
  {
    const float* wb  = w0 + (f * 32 + g * 8) * 3;
    const float* bbp = b0 + f * 32 + g * 8;
#pragma unroll
    for (int q = 0; q < 2; ++q) {
      const float* si = sIn[q];
      f16* aA = actA[q];
#pragma unroll
      for (int it = 0; it < 2; ++it) {
        const int p = lane + it * 64;
        if (p < 72) {
          const float i0 = si[p], i1 = si[p + 1], i2 = si[p + 2];
          f16x4 wv[2];
#pragma unroll
          for (int j = 0; j < 8; ++j) {
            float v = fmaf(wb[j * 3 + 0], i0,
                      fmaf(wb[j * 3 + 1], i1,
                      fmaf(wb[j * 3 + 2], i2, bbp[j])));
            wv[j >> 2][j & 3] = (f16)fmaxf(v, 0.f);
          }
          *(f16x4*)(aA + p * RPAD + g * 8)     = wv[0];
          *(f16x4*)(aA + p * RPAD + g * 8 + 4) = wv[1];
        }
      }
    }
  }
  __syncthreads();

  // ---- phase2: L1 mfma (6 jobs over 4 waves); lastf L0 slices ----
  if (lastf) {
    for (int t = tid; t < 256; t += 256) {
      const int q = t >> 7, tt = t & 127;
      ws[OFF_ST + (bp * 2 + q) * ST_STRIDE + ST_L0 + tt] =
          (float)actA[q][(57 + (tt >> 5)) * RPAD + (tt & 31)];
    }
  }
  {
    // job j: q = j/3, base = {0,32,36}[j%3]; wave g does j=g, and j=g+4 if g<2
    int j = g;
    {
      const int q = j / 3, bi = j % 3;
      mfma_tile2(actA[q], actB[q], 2, (bi == 2) ? 36 : bi * 32, wrow, lane, sBias[0]);
    }
    if (g < 2) {
      j = g + 4;
      const int q = j / 3, bi = j % 3;
      mfma_tile2(actA[q], actB[q], 2, (bi == 2) ? 36 : bi * 32, wrow, lane, sBias[0]);
    }
  }
  __syncthreads();

  // ---- phase3: stage layer-1 weights; lastf L1 slices ----
  stage_wrow(wmid, 1, f, tid, wrow);
  if (lastf) {
    for (int t = tid; t < 512; t += 256) {
      const int q = t >> 8, tt = t & 255;
      ws[OFF_ST + (bp * 2 + q) * ST_STRIDE + ST_L1 + tt] =
          (float)actB[q][(49 + (tt >> 5)) * RPAD + (tt & 31)];
    }
  }
  __syncthreads();

  // ---- phase4: L2 mfma (4 jobs, all waves) ----
  mfma_tile2(actB[g >> 1], actA[g >> 1], 4, (g & 1) * 28, wrow, lane, sBias[1]);
  __syncthreads();

  // ---- phase5: stage layer-2 weights; lastf L2 slices ----
  stage_wrow(wmid, 2, f, tid, wrow);
  if (lastf) {
    for (int t = tid; t < 1024; t += 256) {
      const int q = t >> 9, tt = t & 511;
      ws[OFF_ST + (bp * 2 + q) * ST_STRIDE + ST_L2 + tt] =
          (float)actA[q][(33 + (tt >> 5)) * RPAD + (tt & 31)];
    }
  }
  __syncthreads();

  // ---- phase6: L3 mfma (4 jobs, all waves) ----
  mfma_tile2(actA[g >> 1], actB[g >> 1], 8, (g & 1) * 12, wrow, lane, sBias[2]);
  __syncthreads();

  // ---- phase7: lastf L3 slices; L4 (both batches) ----
  if (lastf) {
    for (int t = tid; t < 1728; t += 256) {
      const int q = t / 864, tt = t % 864;
      ws[OFF_ST + (bp * 2 + q) * ST_STRIDE + ST_L3 + tt] =
          (float)actB[q][(1 + (tt >> 5)) * RPAD + (tt & 31)];
    }
  }
  if (tid < 24) {
    const int q = tid / 12, p = tid % 12;
    const int b = bp * 2 + q;
    float acc = blast[f];
    const float* wl = wlast + f * 96;
    const f16* aB = actB[q];
#pragma unroll
    for (int k = 0; k < 3; ++k) {
      const int row = p + 16 * k;
#pragma unroll
      for (int ci0 = 0; ci0 < 32; ci0 += 4) {
        f16x4 av = *(const f16x4*)(aB + row * RPAD + ci0);
#pragma unroll
        for (int e = 0; e < 4; ++e)
          acc = fmaf(wl[(ci0 + e) * 3 + k], (float)av[e], acc);
      }
    }
    if (!lastf) {
      ws[OFF_H4 + b * 768 + (p >> 2) * 256 + f * 4 + (p & 3)] = acc;
    } else {
      ws[OFF_H4 + b * 768 + (p >> 2) * 256 + 63 * 4 + (p & 3)] = 0.f;
      if (p == 0) ws[OFF_H40 + b] = acc;
    }
  }
}

// ---------------- kernel B: sequential feature-63 chain (R16) --------------

__device__ __forceinline__ float fd2(h2 a, h2 b, float c) {
#if __has_builtin(__builtin_amdgcn_fdot2)
  return __builtin_amdgcn_fdot2(a, b, c, false);
#else
  return fmaf((float)a[0], (float)b[0], fmaf((float)a[1], (float)b[1], c));
#endif
}

__device__ __forceinline__ float dotv(f16x8 w, f16x8 a, float acc) {
  h2 w0 = {w[0], w[1]}, a0 = {a[0], a[1]};
  h2 w1 = {w[2], w[3]}, a1 = {a[2], a[3]};
  h2 w2 = {w[4], w[5]}, a2 = {a[4], a[5]};
  h2 w3 = {w[6], w[7]}, a3 = {a[6], a[7]};
  acc = fd2(w0, a0, acc);
  acc = fd2(w1, a1, acc);
  acc = fd2(w2, a2, acc);
  acc = fd2(w3, a3, acc);
  return acc;
}

__device__ __forceinline__ f16x8 combineh(f16x8 lo, f16x8 hi) {
  f16x8 s = lo + hi;
#pragma unroll
  for (int i = 0; i < 8; ++i) s[i] = (s[i] > (f16)0.f) ? s[i] : (f16)0.f;
  return s;
}

__device__ __forceinline__ void load16f(const float* p, float* r) {
  const float4* q = reinterpret_cast<const float4*>(p);
  const float4 v0 = q[0], v1 = q[1], v2 = q[2], v3 = q[3];
  r[0]=v0.x;  r[1]=v0.y;  r[2]=v0.z;  r[3]=v0.w;
  r[4]=v1.x;  r[5]=v1.y;  r[6]=v1.z;  r[7]=v1.w;
  r[8]=v2.x;  r[9]=v2.y;  r[10]=v2.z; r[11]=v2.w;
  r[12]=v3.x; r[13]=v3.y; r[14]=v3.z; r[15]=v3.w;
}

__global__ __launch_bounds__(256, 1) void tcn_seq(
    const float* __restrict__ x,
    const float* __restrict__ linW,
    const float* __restrict__ ws, float* __restrict__ out)
{
  const int b = blockIdx.x;
  const int tid = threadIdx.x;
  const int wid = tid >> 6;
  const int lane = tid & 63;
  const int c = lane & 31;
  const int h = (lane >> 5) & 1;
  const int cib = h * 16;

  __shared__ __align__(16) f16 L0h[15 * 32];
  __shared__ __align__(16) f16 L1p[2][19 * 32];
  __shared__ __align__(16) f16 L2p[2][27 * 32];
  __shared__ __align__(16) f16 wseqh[18 * 64 * 8];
  __shared__ __align__(16) float qs[32];
  __shared__ float preArr[12];

  const float* stp = ws + OFF_ST + b * ST_STRIDE;

  // ---- waves 1-3: parallel staging, then exit ----
  if (wid == 1) {
    const f16* rech = (const f16*)(ws + OFF_RECH);
#pragma unroll
    for (int q = 0; q < 18; ++q)
      *(f16x8*)(wseqh + (q * 64 + lane) * 8) = *(const f16x8*)(rech + (q * 64 + lane) * 8);
  } else if (wid == 2) {
    for (int t = lane; t < 128; t += 64) L0h[t] = (f16)stp[ST_L0 + t];
    for (int t = lane; t < 256; t += 64) { L1p[0][t] = (f16)stp[ST_L1 + t]; L1p[1][t] = (f16)0.f; }
  } else if (wid == 3) {
    for (int t = lane; t < 512; t += 64) { L2p[0][t] = (f16)stp[ST_L2 + t]; L2p[1][t] = (f16)0.f; }
  }
  if (wid != 0) { __syncthreads(); return; }

  // ---- wave 0: params + accv ----
  float prm[16];
  {
    const float* tab = ws + OFF_PRM;
#pragma unroll
    for (int q = 0; q < 4; ++q) {
      const float4 v = *reinterpret_cast<const float4*>(tab + (q * 64 + lane) * 4);
      prm[q * 4 + 0] = v.x; prm[q * 4 + 1] = v.y;
      prm[q * 4 + 2] = v.z; prm[q * 4 + 3] = v.w;
    }
  }
  const float w00 = prm[0],  w01 = prm[1],  w02 = prm[2],  b00 = prm[3];
  const float bm0 = prm[4],  bm1 = prm[5],  bm2 = prm[6];
  const float wl0c = prm[7], wl1c = prm[8], wl2c = prm[9];
  const float bl = prm[10],  lw63 = prm[11], lb0 = prm[12];

  const float xv61 = x[(b * 63 + 61) * 64 + 63];
  const float xv62 = x[(b * 63 + 62) * 64 + 63];
  const float h40v = ws[OFF_H40 + b];

  float accv[12];
  {
    float lw = 0.f, lwx = 0.f;
    if (lane < 63) { lw = linW[lane]; lwx = linW[64 + lane]; }
    float h4v[12], xv[12];
#pragma unroll
    for (int q = 0; q < 3; ++q) {
      const float4 hv  = *reinterpret_cast<const float4*>(ws + OFF_H4 + b * 768 + q * 256 + lane * 4);
      const float4 xvv = *reinterpret_cast<const float4*>(ws + OFF_XFT + b * 768 + q * 256 + lane * 4);
      h4v[q*4+0] = hv.x; h4v[q*4+1] = hv.y; h4v[q*4+2] = hv.z; h4v[q*4+3] = hv.w;
      xv[q*4+0] = xvv.x; xv[q*4+1] = xvv.y; xv[q*4+2] = xvv.z; xv[q*4+3] = xvv.w;
    }
#pragma unroll
    for (int i = 0; i < 12; ++i) accv[i] = fmaf(lw, h4v[i], lwx * xv[i]);

    if (lane < 32) {
#pragma unroll
      for (int i = 1; i < 12; ++i) {
        const float qc = fmaf(wl0c, stp[ST_L3 + (i - 1) * 32 + lane],
                              wl1c * stp[ST_L3 + (i + 15) * 32 + lane]);
        accv[i] = fmaf(lw63, qc, accv[i]);
      }
    }
#pragma unroll
    for (int r = 1; r < 64; r <<= 1) {
#pragma unroll
      for (int i = 0; i < 12; ++i) accv[i] += __shfl_xor(accv[i], r);
    }
  }
  if (lane == 0) {
#pragma unroll
    for (int i = 1; i < 12; ++i) preArr[i] = accv[i] + lb0 + lw63 * bl;
  }
  __syncthreads();   // pairs with waves 1-3's barrier; staging visible

  // opaque pointer: keep per-iteration wseqh reads (no LICM re-hoist)
  const f16* wbase = wseqh;
  asm volatile("" : "+v"(wbase));

  // ---- step 0 ----
  const float out0 = fmaf(lw63, h40v, accv[0] + lb0);
  if (lane == 0) out[b * 12 + 0] = out0;
  float o1 = out0, o2 = xv62, o3 = xv61;

  // ---- steps 1..11 (rolled; f16 data, f32 accum) ----
#pragma unroll 1
  for (int s = 1; s < 12; ++s) {
    const float preS = preArr[s];

    const float nL0 = fmaxf(fmaf(w00, o3, fmaf(w01, o2, fmaf(w02, o1, b00))), 0.f);
    L0h[(3 + s) * 32 + c] = (f16)nL0;

    // ---- L1 @ 56+s ----
    float v1;
    {
      const f16* wp = wbase + (0 * 6 * 64 + lane) * 8;
      f16x8 W0 = *(const f16x8*)(wp);
      f16x8 W1 = *(const f16x8*)(wp + 64 * 8);
      f16x8 W2 = *(const f16x8*)(wp + 2 * 64 * 8);
      f16x8 W3 = *(const f16x8*)(wp + 3 * 64 * 8);
      f16x8 W4 = *(const f16x8*)(wp + 4 * 64 * 8);
      f16x8 W5 = *(const f16x8*)(wp + 5 * 64 * 8);
      const f16* r0p = L0h + (s - 1) * 32 + cib;
      const f16* r1p = L0h + (s + 1) * 32 + cib;
      const f16* np  = L0h + (3 + s) * 32 + cib;
      f16x8 R0a = *(const f16x8*)r0p, R0b = *(const f16x8*)(r0p + 8);
      f16x8 R1a = *(const f16x8*)r1p, R1b = *(const f16x8*)(r1p + 8);
      f16x8 Na  = *(const f16x8*)np,  Nb  = *(const f16x8*)(np + 8);
      float a0 = dotv(W0, R0a, 0.f), a1 = dotv(W1, R0b, 0.f);
      a0 = dotv(W2, R1a, a0);        a1 = dotv(W3, R1b, a1);
      a0 = dotv(W4, Na, a0);         a1 = dotv(W5, Nb, a1);
      v1 = a0 + a1 + (h == 0 ? bm0 : 0.f);
    }
    L1p[h][(7 + s) * 32 + c] = (f16)v1;

    // ---- L2 @ 48+s ----
    float v2;
    {
      const f16* wp = wbase + (1 * 6 * 64 + lane) * 8;
      f16x8 W0 = *(const f16x8*)(wp);
      f16x8 W1 = *(const f16x8*)(wp + 64 * 8);
      f16x8 W2 = *(const f16x8*)(wp + 2 * 64 * 8);
      f16x8 W3 = *(const f16x8*)(wp + 3 * 64 * 8);
      f16x8 W4 = *(const f16x8*)(wp + 4 * 64 * 8);
      f16x8 W5 = *(const f16x8*)(wp + 5 * 64 * 8);
      const int i0 = (s - 1) * 32 + cib, i1 = (s + 3) * 32 + cib, in = (7 + s) * 32 + cib;
      f16x8 R0a = combineh(*(const f16x8*)(&L1p[0][i0]),     *(const f16x8*)(&L1p[1][i0]));
      f16x8 R0b = combineh(*(const f16x8*)(&L1p[0][i0 + 8]), *(const f16x8*)(&L1p[1][i0 + 8]));
      f16x8 R1a = combineh(*(const f16x8*)(&L1p[0][i1]),     *(const f16x8*)(&L1p[1][i1]));
      f16x8 R1b = combineh(*(const f16x8*)(&L1p[0][i1 + 8]), *(const f16x8*)(&L1p[1][i1 + 8]));
      f16x8 Na  = combineh(*(const f16x8*)(&L1p[0][in]),     *(const f16x8*)(&L1p[1][in]));
      f16x8 Nb  = combineh(*(const f16x8*)(&L1p[0][in + 8]), *(const f16x8*)(&L1p[1][in + 8]));
      float a0 = dotv(W0, R0a, 0.f), a1 = dotv(W1, R0b, 0.f);
      a0 = dotv(W2, R1a, a0);        a1 = dotv(W3, R1b, a1);
      a0 = dotv(W4, Na, a0);         a1 = dotv(W5, Nb, a1);
      v2 = a0 + a1 + (h == 0 ? bm1 : 0.f);
    }
    L2p[h][(15 + s) * 32 + c] = (f16)v2;

    // ---- L3 @ 32+s ----
    float v3;
    {
      const f16* wp = wbase + (2 * 6 * 64 + lane) * 8;
      f16x8 W0 = *(const f16x8*)(wp);
      f16x8 W1 = *(const f16x8*)(wp + 64 * 8);
      f16x8 W2 = *(const f16x8*)(wp + 2 * 64 * 8);
      f16x8 W3 = *(const f16x8*)(wp + 3 * 64 * 8);
      f16x8 W4 = *(const f16x8*)(wp + 4 * 64 * 8);
      f16x8 W5 = *(const f16x8*)(wp + 5 * 64 * 8);
      const int i0 = (s - 1) * 32 + cib, i1 = (s + 7) * 32 + cib, in = (15 + s) * 32 + cib;
      f16x8 R0a = combineh(*(const f16x8*)(&L2p[0][i0]),     *(const f16x8*)(&L2p[1][i0]));
      f16x8 R0b = combineh(*(const f16x8*)(&L2p[0][i0 + 8]), *(const f16x8*)(&L2p[1][i0 + 8]));
      f16x8 R1a = combineh(*(const f16x8*)(&L2p[0][i1]),     *(const f16x8*)(&L2p[1][i1]));
      f16x8 R1b = combineh(*(const f16x8*)(&L2p[0][i1 + 8]), *(const f16x8*)(&L2p[1][i1 + 8]));
      f16x8 Na  = combineh(*(const f16x8*)(&L2p[0][in]),     *(const f16x8*)(&L2p[1][in]));
      f16x8 Nb  = combineh(*(const f16x8*)(&L2p[0][in + 8]), *(const f16x8*)(&L2p[1][in + 8]));
      float a0 = dotv(W0, R0a, 0.f), a1 = dotv(W1, R0b, 0.f);
      a0 = dotv(W2, R1a, a0);        a1 = dotv(W3, R1b, a1);
      a0 = dotv(W4, Na, a0);         a1 = dotv(W5, Nb, a1);
      v3 = a0 + a1 + (h == 0 ? bm2 : 0.f);
    }
    v3 += __shfl_xor(v3, 32);
    const float nL3 = fmaxf(v3, 0.f);

    // ---- L4 @ s: tap2 only; sum over co via LDS broadcast roundtrip ----
    if (h == 0) qs[c] = wl2c * nL3;
    float qa[16], qb[16];
    load16f(qs, qa); load16f(qs + 16, qb);
    float s0 = 0.f, s1 = 0.f, s2 = 0.f, s3 = 0.f;
#pragma unroll
    for (int i = 0; i < 16; i += 4) {
      s0 += qa[i + 0] + qb[i + 0];
      s1 += qa[i + 1] + qb[i + 1];
      s2 += qa[i + 2] + qb[i + 2];
      s3 += qa[i + 3] + qb[i + 3];
    }
    const float S = (s0 + s1) + (s2 + s3);
    const float outs = fmaf(lw63, S, preS);
    if (lane == 0) out[b * 12 + s] = outs;
    o3 = o2; o2 = o1; o1 = outs;
  }
}

// ---------------- launcher ----------------

extern "C" void kernel_launch(void* const* d_in, const int* in_sizes, int n_in,
                              void* d_out, int out_size, void* d_ws, size_t ws_size,
                              hipStream_t stream) {
  const float* x     = (const float*)d_in[0];
  const float* xfc   = (const float*)d_in[1];
  const float* w0    = (const float*)d_in[2];
  const float* b0    = (const float*)d_in[3];
  const float* wmid  = (const float*)d_in[4];
  const float* bmid  = (const float*)d_in[5];
  const float* wlast = (const float*)d_in[6];
  const float* blast = (const float*)d_in[7];
  const float* linW  = (const float*)d_in[8];
  const float* linb  = (const float*)d_in[9];
  float* out = (float*)d_out;
  float* ws  = (float*)d_ws;

  // 2048 batch-paired compute blocks + 232 table tail blocks
  tcn_pre<<<NCOMP + 232, 256, 0, stream>>>(
      x, xfc, w0, b0, wmid, bmid, wlast, blast, linW, linb, ws);
  tcn_seq<<<64, 256, 0, stream>>>(x, linW, ws, out);
}